// Round 1
// baseline (269.619 us; speedup 1.0000x reference)
//
#include <hip/hip_runtime.h>
#include <hip/hip_bf16.h>
#include <math.h>
#include <stdint.h>

// MultiHeadDenseAttention: B=2, H=16, N=2048, D=64, F=1024, M=2048
//  value = x @ Wv^T                  (GEMM, writes V^T per head: vt[bh][d][m])
//  hid   = relu(xh @ W1^T + b1)      (small per-head GEMM, fp32)
//  attn  = softmax(hid @ W2^T + b2)  (flash-style, fused)
//  out_h = attn @ vh                 (fused with above)
//  out   = merge(out_h) @ Wo^T       (GEMM, fp32 out)

typedef __attribute__((ext_vector_type(8))) short bf16x8;
typedef __attribute__((ext_vector_type(4))) float f32x4;

__device__ __forceinline__ unsigned short f2bf(float f) {
  union { float f; unsigned u; } v; v.f = f;
  unsigned r = v.u + 0x7FFFu + ((v.u >> 16) & 1u);   // round-to-nearest-even
  return (unsigned short)(r >> 16);
}

// ---------------- fp32 -> bf16 convert ----------------
__global__ __launch_bounds__(256) void conv_bf16(const float* __restrict__ src,
                                                 unsigned short* __restrict__ dst, int nq) {
  // nq = number of 4-element quads
  int stride = gridDim.x * blockDim.x;
  for (int q = blockIdx.x * blockDim.x + threadIdx.x; q < nq; q += stride) {
    float4 v = *(const float4*)(src + (size_t)q * 4);
    unsigned short p0 = f2bf(v.x), p1 = f2bf(v.y), p2 = f2bf(v.z), p3 = f2bf(v.w);
    uint2 u;
    u.x = (unsigned)p0 | ((unsigned)p1 << 16);
    u.y = (unsigned)p2 | ((unsigned)p3 << 16);
    *(uint2*)(dst + (size_t)q * 4) = u;
  }
}

// ---------------- shared staging/frag helpers ----------------
// Stage a 64-row x 128-byte tile into 8KB of LDS via global_load_lds.
// LDS layout: linear rows of 128B, with XOR swizzle applied on the GLOBAL side:
//   LDS(row, chunk c') holds global chunk c' ^ (row&7)   (c' = 16B chunk index 0..7)
// Each of the 4 waves issues 2 instructions (1KB each).
__device__ __forceinline__ void stage64(const char* g, size_t ldbytes, char* lds,
                                        int w, int lane) {
#pragma unroll
  for (int t = 0; t < 2; ++t) {
    int row  = w * 16 + t * 8 + (lane >> 3);      // row & 7 == lane>>3
    int csrc = (lane & 7) ^ (lane >> 3);          // inverse-swizzled source chunk
    const char* src = g + (size_t)row * ldbytes + (csrc << 4);
    char* dst = lds + ((w * 2 + t) << 10);        // wave-uniform base; HW adds lane*16
    __builtin_amdgcn_global_load_lds((const __attribute__((address_space(1))) void*)src,
                                     (__attribute__((address_space(3))) void*)dst,
                                     16, 0, 0);
  }
}

// Read an MFMA 16x16x32 operand fragment (8 bf16, k-contiguous) from a staged tile.
// Lane l reads row, k-chunk = kt*4 + (l>>4), with the matching XOR swizzle.
__device__ __forceinline__ bf16x8 rdfrag(const char* lds, int row, int kt, int lane) {
  int c = ((kt << 2) + (lane >> 4)) ^ (row & 7);
  return *(const bf16x8*)(lds + row * 128 + (c << 4));
}

// ---------------- GEMM: C = A @ B^T, A[M][K] bf16, B[N][K] bf16 ----------------
// 64x64 tile, 4 waves, wave w owns rows w*16..w*16+15 and all 64 cols.
// MODE 0: store bf16 transposed-per-head into vt[bh*64+d][2048] (value projection)
// MODE 1: store fp32 row-major [M][1024] (final output)
template<int MODE>
__global__ __launch_bounds__(256) void gemm_bt(const unsigned short* __restrict__ A,
                                               const unsigned short* __restrict__ B,
                                               void* __restrict__ C, int K) {
  __shared__ __attribute__((aligned(16))) char As[8192];
  __shared__ __attribute__((aligned(16))) char Bs[8192];
  int tid = threadIdx.x, w = tid >> 6, lane = tid & 63;
  int bm = blockIdx.x, bn = blockIdx.y;
  const char* Ab = (const char*)A + (size_t)bm * 64 * (K * 2);
  const char* Bb = (const char*)B + (size_t)bn * 64 * (K * 2);
  f32x4 acc[4] = {};
  int nsteps = K >> 6;
  for (int kk = 0; kk < nsteps; ++kk) {
    __syncthreads();
    stage64(Ab + (size_t)kk * 128, (size_t)K * 2, As, w, lane);
    stage64(Bb + (size_t)kk * 128, (size_t)K * 2, Bs, w, lane);
    __syncthreads();
#pragma unroll
    for (int kt = 0; kt < 2; ++kt) {
      bf16x8 a = rdfrag(As, w * 16 + (lane & 15), kt, lane);
#pragma unroll
      for (int nj = 0; nj < 4; ++nj) {
        bf16x8 b = rdfrag(Bs, nj * 16 + (lane & 15), kt, lane);
        acc[nj] = __builtin_amdgcn_mfma_f32_16x16x32_bf16(a, b, acc[nj], 0, 0, 0);
      }
    }
  }
  int g = lane >> 4, fr = lane & 15;
  if (MODE == 0) {
    // rows are (b*2048+n), cols f = bn*64 + nj*16 + fr; one head per bn (h = bn)
    unsigned short* vt = (unsigned short*)C;
    int growbase = bm * 64 + w * 16 + g * 4;      // 4 consecutive n per lane (r=0..3)
    int b = growbase >> 11;
    int n = growbase & 2047;
#pragma unroll
    for (int nj = 0; nj < 4; ++nj) {
      int d = nj * 16 + fr;
      unsigned short p0 = f2bf(acc[nj][0]), p1 = f2bf(acc[nj][1]);
      unsigned short p2 = f2bf(acc[nj][2]), p3 = f2bf(acc[nj][3]);
      uint2 u;
      u.x = (unsigned)p0 | ((unsigned)p1 << 16);
      u.y = (unsigned)p2 | ((unsigned)p3 << 16);
      *(uint2*)(vt + ((size_t)((b * 16 + bn) * 64 + d)) * 2048 + n) = u;
    }
  } else {
    float* Cf = (float*)C;
    int grow = bm * 64 + w * 16 + g * 4;
#pragma unroll
    for (int nj = 0; nj < 4; ++nj) {
#pragma unroll
      for (int r = 0; r < 4; ++r) {
        Cf[(size_t)(grow + r) * 1024 + bn * 64 + nj * 16 + fr] = acc[nj][r];
      }
    }
  }
}

// ---------------- hid = relu(xh @ W1^T + b1), fp32 compute, bf16 out ----------------
// One wave = one (b,h,n) row; lane = output feature e (64 of them). K = 64.
__global__ __launch_bounds__(256) void hid_kernel(const float* __restrict__ x,
                                                  const float* __restrict__ W1,
                                                  const float* __restrict__ b1,
                                                  unsigned short* __restrict__ hid) {
  __shared__ float W1t[64 * 64];                  // transposed: W1t[d][e]
  int tid = threadIdx.x;
  for (int i = tid; i < 4096; i += 256) {
    int e = i >> 6, d = i & 63;
    W1t[d * 64 + e] = W1[i];
  }
  __syncthreads();
  int w = tid >> 6, e = tid & 63;
  int rid = blockIdx.x * 4 + w;                   // rid = (b*16+h)*2048 + n
  int b = rid >> 15, h = (rid >> 11) & 15, n = rid & 2047;
  const float* xrow = x + (size_t)(b * 2048 + n) * 1024 + h * 64;
  float acc = b1[e];
#pragma unroll
  for (int d = 0; d < 64; ++d)
    acc = fmaf(xrow[d], W1t[d * 64 + e], acc);    // W1t read: banks fully spread
  acc = fmaxf(acc, 0.f);
  hid[(size_t)rid * 64 + e] = f2bf(acc);
}

// ---------------- fused dense attention (flash-style) ----------------
// Per block: one (b,h), 64 Q rows (qt). 4 waves, wave owns 16 Q rows.
// Loop over m in steps of 64: S = Q@W2^T + b2 (MFMA), online softmax, O += P@V.
__global__ __launch_bounds__(256) void flash_kernel(const unsigned short* __restrict__ hid,
                                                    const unsigned short* __restrict__ w2b,
                                                    const float* __restrict__ b2,
                                                    const unsigned short* __restrict__ vt,
                                                    unsigned short* __restrict__ aout) {
  __shared__ __attribute__((aligned(16))) char Qs[8192];
  __shared__ __attribute__((aligned(16))) char Ks[8192];
  __shared__ __attribute__((aligned(16))) char Vs[8192];
  __shared__ __attribute__((aligned(16))) char Ps[8192];   // per-wave 2KB P tiles
  int tid = threadIdx.x, w = tid >> 6, lane = tid & 63;
  int qt = blockIdx.x, bh = blockIdx.y;
  int g = lane >> 4, fr = lane & 15;

  stage64((const char*)(hid + ((size_t)bh * 2048 + qt * 64) * 64), 128, Qs, w, lane);
  __syncthreads();
  bf16x8 qf0 = rdfrag(Qs, w * 16 + fr, 0, lane);
  bf16x8 qf1 = rdfrag(Qs, w * 16 + fr, 1, lane);

  f32x4 o[4] = {};
  float mrun[4] = {-INFINITY, -INFINITY, -INFINITY, -INFINITY};
  float lrun[4] = {0.f, 0.f, 0.f, 0.f};
  char* myPs = Ps + (w << 11);

  for (int mt = 0; mt < 32; ++mt) {
    __syncthreads();
    stage64((const char*)w2b + (size_t)mt * 8192, 128, Ks, w, lane);
    stage64((const char*)vt + (size_t)bh * 64 * 4096 + (size_t)mt * 128, 4096, Vs, w, lane);
    __syncthreads();

    // S tile: rows = q (D-layout row g*4+r), cols = m local (l&15 per 16-subtile j)
    f32x4 s[4] = {};
#pragma unroll
    for (int j = 0; j < 4; ++j) {
      bf16x8 kb0 = rdfrag(Ks, j * 16 + fr, 0, lane);
      s[j] = __builtin_amdgcn_mfma_f32_16x16x32_bf16(qf0, kb0, s[j], 0, 0, 0);
      bf16x8 kb1 = rdfrag(Ks, j * 16 + fr, 1, lane);
      s[j] = __builtin_amdgcn_mfma_f32_16x16x32_bf16(qf1, kb1, s[j], 0, 0, 0);
    }
#pragma unroll
    for (int j = 0; j < 4; ++j) {
      float bv = b2[mt * 64 + j * 16 + fr];
#pragma unroll
      for (int r = 0; r < 4; ++r) s[j][r] += bv;
    }

    // online softmax per q-row r (row-max across j and the 16 lanes of the group)
#pragma unroll
    for (int r = 0; r < 4; ++r) {
      float mx = fmaxf(fmaxf(s[0][r], s[1][r]), fmaxf(s[2][r], s[3][r]));
      mx = fmaxf(mx, __shfl_xor(mx, 1));
      mx = fmaxf(mx, __shfl_xor(mx, 2));
      mx = fmaxf(mx, __shfl_xor(mx, 4));
      mx = fmaxf(mx, __shfl_xor(mx, 8));
      float mnew = fmaxf(mrun[r], mx);
      float sc = __expf(mrun[r] - mnew);           // exp(-inf)=0 on first tile
      mrun[r] = mnew;
      float ps = 0.f;
#pragma unroll
      for (int j = 0; j < 4; ++j) {
        float p = __expf(s[j][r] - mnew);
        s[j][r] = p;
        ps += p;
      }
      lrun[r] = lrun[r] * sc + ps;                 // per-lane partial row sum
#pragma unroll
      for (int dj = 0; dj < 4; ++dj) o[dj][r] *= sc;
    }

    // P (D-layout) -> bf16 -> per-wave LDS, swizzled to match rdfrag
#pragma unroll
    for (int r = 0; r < 4; ++r) {
      int row = g * 4 + r;
      int swz = (row & 7) << 4;
#pragma unroll
      for (int j = 0; j < 4; ++j) {
        int byteoff = (row << 7) + (((((j << 4) + fr) << 1)) ^ swz);
        *(unsigned short*)(myPs + byteoff) = f2bf(s[j][r]);
      }
    }

    // O += P @ V   (A-frag = P rows q, B-frag = Vt rows d)
#pragma unroll
    for (int kt = 0; kt < 2; ++kt) {
      bf16x8 pf = rdfrag(myPs, fr, kt, lane);
#pragma unroll
      for (int dj = 0; dj < 4; ++dj) {
        bf16x8 vb = rdfrag(Vs, dj * 16 + fr, kt, lane);
        o[dj] = __builtin_amdgcn_mfma_f32_16x16x32_bf16(pf, vb, o[dj], 0, 0, 0);
      }
    }
  }

  // finalize: reduce row sums across the 16-lane group, normalize, store bf16
  float inv[4];
#pragma unroll
  for (int r = 0; r < 4; ++r) {
    float l = lrun[r];
    l += __shfl_xor(l, 1);
    l += __shfl_xor(l, 2);
    l += __shfl_xor(l, 4);
    l += __shfl_xor(l, 8);
    inv[r] = 1.f / l;
  }
  int b = bh >> 4, h = bh & 15;
  int nbase = qt * 64 + w * 16 + g * 4;
#pragma unroll
  for (int dj = 0; dj < 4; ++dj) {
    int f = h * 64 + dj * 16 + fr;
#pragma unroll
    for (int r = 0; r < 4; ++r) {
      aout[((size_t)(b * 2048 + nbase + r)) * 1024 + f] = f2bf(o[dj][r] * inv[r]);
    }
  }
}

// ---------------- launch ----------------
extern "C" void kernel_launch(void* const* d_in, const int* in_sizes, int n_in,
                              void* d_out, int out_size, void* d_ws, size_t ws_size,
                              hipStream_t stream) {
  (void)in_sizes; (void)n_in; (void)out_size; (void)ws_size;
  const float* x  = (const float*)d_in[0];
  const float* W1 = (const float*)d_in[1];
  const float* b1 = (const float*)d_in[2];
  const float* W2 = (const float*)d_in[3];
  const float* b2 = (const float*)d_in[4];
  const float* Wv = (const float*)d_in[5];
  const float* Wo = (const float*)d_in[6];
  float* out = (float*)d_out;

  char* ws = (char*)d_ws;
  unsigned short* xb   = (unsigned short*)(ws);             // x bf16      8 MB
  unsigned short* wvb  = (unsigned short*)(ws +  8388608);  // Wv bf16     2 MB
  unsigned short* wob  = (unsigned short*)(ws + 10485760);  // Wo bf16     2 MB
  unsigned short* w2b  = (unsigned short*)(ws + 12582912);  // W2 bf16   256 KB
  unsigned short* hidb = (unsigned short*)(ws + 12845056);  // hid bf16    8 MB
  unsigned short* vt   = (unsigned short*)(ws + 21233664);  // V^T bf16    8 MB
  unsigned short* aout = (unsigned short*)(ws + 29622272);  // out_h bf16  8 MB
  // total ws usage: 38,010,880 bytes

  conv_bf16<<<1024, 256, 0, stream>>>(x,  xb,  4194304 / 4);
  conv_bf16<<<1024, 256, 0, stream>>>(Wv, wvb, 1048576 / 4);
  conv_bf16<<<1024, 256, 0, stream>>>(Wo, wob, 1048576 / 4);
  conv_bf16<<< 128, 256, 0, stream>>>(W2, w2b,  131072 / 4);

  // value = x @ Wv^T -> vt[bh][d][m]
  gemm_bt<0><<<dim3(64, 16), 256, 0, stream>>>(xb, wvb, (void*)vt, 1024);
  // hid = relu(xh @ W1^T + b1)
  hid_kernel<<<16384, 256, 0, stream>>>(x, W1, b1, hidb);
  // fused softmax(hid @ W2^T + b2) @ V -> aout (merged heads, bf16)
  flash_kernel<<<dim3(32, 32), 256, 0, stream>>>(hidb, w2b, b2, vt, aout);
  // out = aout @ Wo^T (fp32)
  gemm_bt<1><<<dim3(64, 16), 256, 0, stream>>>(aout, wob, (void*)out, 1024);
}

// Round 2
// 147.704 us; speedup vs baseline: 1.8254x; 1.8254x over previous
//
#include <hip/hip_runtime.h>
#include <hip/hip_bf16.h>
#include <math.h>
#include <stdint.h>

// MultiHeadDenseAttention: B=2, H=16, N=2048, D=64, F=1024, M=2048
//  value = x @ Wv^T                  (GEMM, writes V^T per head: vt[bh][d][m])
//  hid   = relu(xh @ W1^T + b1)      (FUSED into flash prologue, MFMA)
//  attn  = softmax(hid @ W2^T + b2)  (flash-style, fused)
//  out_h = attn @ vh                 (fused with above)
//  out   = merge(out_h) @ Wo^T       (GEMM, fp32 out)

typedef __attribute__((ext_vector_type(8))) short bf16x8;
typedef __attribute__((ext_vector_type(4))) float f32x4;

__device__ __forceinline__ unsigned short f2bf(float f) {
  union { float f; unsigned u; } v; v.f = f;
  unsigned r = v.u + 0x7FFFu + ((v.u >> 16) & 1u);   // round-to-nearest-even
  return (unsigned short)(r >> 16);
}

// ---------------- fp32 -> bf16 convert ----------------
__global__ __launch_bounds__(256) void conv_bf16(const float* __restrict__ src,
                                                 unsigned short* __restrict__ dst, int nq) {
  // nq = number of 4-element quads
  int stride = gridDim.x * blockDim.x;
  for (int q = blockIdx.x * blockDim.x + threadIdx.x; q < nq; q += stride) {
    float4 v = *(const float4*)(src + (size_t)q * 4);
    unsigned short p0 = f2bf(v.x), p1 = f2bf(v.y), p2 = f2bf(v.z), p3 = f2bf(v.w);
    uint2 u;
    u.x = (unsigned)p0 | ((unsigned)p1 << 16);
    u.y = (unsigned)p2 | ((unsigned)p3 << 16);
    *(uint2*)(dst + (size_t)q * 4) = u;
  }
}

// ---------------- shared staging/frag helpers ----------------
// Stage a 64-row x 128-byte tile into 8KB of LDS via global_load_lds.
// LDS layout: linear rows of 128B, with XOR swizzle applied on the GLOBAL side:
//   LDS(row, chunk c') holds global chunk c' ^ (row&7)   (c' = 16B chunk index 0..7)
// Each of the 4 waves issues 2 instructions (1KB each).
__device__ __forceinline__ void stage64(const char* g, size_t ldbytes, char* lds,
                                        int w, int lane) {
#pragma unroll
  for (int t = 0; t < 2; ++t) {
    int row  = w * 16 + t * 8 + (lane >> 3);      // row & 7 == lane>>3
    int csrc = (lane & 7) ^ (lane >> 3);          // inverse-swizzled source chunk
    const char* src = g + (size_t)row * ldbytes + (csrc << 4);
    char* dst = lds + ((w * 2 + t) << 10);        // wave-uniform base; HW adds lane*16
    __builtin_amdgcn_global_load_lds((const __attribute__((address_space(1))) void*)src,
                                     (__attribute__((address_space(3))) void*)dst,
                                     16, 0, 0);
  }
}

// Read an MFMA 16x16x32 operand fragment (8 bf16, k-contiguous) from a staged tile.
// Lane l reads row, k-chunk = kt*4 + (l>>4), with the matching XOR swizzle.
__device__ __forceinline__ bf16x8 rdfrag(const char* lds, int row, int kt, int lane) {
  int c = ((kt << 2) + (lane >> 4)) ^ (row & 7);
  return *(const bf16x8*)(lds + row * 128 + (c << 4));
}

// ---------------- GEMM: C = A @ B^T, A[M][K] bf16, B[N][K] bf16 ----------------
// 64x64 tile, 4 waves, wave w owns rows w*16..w*16+15 and all 64 cols.
// MODE 0: store bf16 transposed-per-head into vt[bh*64+d][2048] (value projection)
// MODE 1: store fp32 row-major [M][1024] (final output)
template<int MODE>
__global__ __launch_bounds__(256) void gemm_bt(const unsigned short* __restrict__ A,
                                               const unsigned short* __restrict__ B,
                                               void* __restrict__ C, int K) {
  __shared__ __attribute__((aligned(16))) char As[8192];
  __shared__ __attribute__((aligned(16))) char Bs[8192];
  int tid = threadIdx.x, w = tid >> 6, lane = tid & 63;
  int bm = blockIdx.x, bn = blockIdx.y;
  const char* Ab = (const char*)A + (size_t)bm * 64 * (K * 2);
  const char* Bb = (const char*)B + (size_t)bn * 64 * (K * 2);
  f32x4 acc[4] = {};
  int nsteps = K >> 6;
  for (int kk = 0; kk < nsteps; ++kk) {
    __syncthreads();
    stage64(Ab + (size_t)kk * 128, (size_t)K * 2, As, w, lane);
    stage64(Bb + (size_t)kk * 128, (size_t)K * 2, Bs, w, lane);
    __syncthreads();
#pragma unroll
    for (int kt = 0; kt < 2; ++kt) {
      bf16x8 a = rdfrag(As, w * 16 + (lane & 15), kt, lane);
#pragma unroll
      for (int nj = 0; nj < 4; ++nj) {
        bf16x8 b = rdfrag(Bs, nj * 16 + (lane & 15), kt, lane);
        acc[nj] = __builtin_amdgcn_mfma_f32_16x16x32_bf16(a, b, acc[nj], 0, 0, 0);
      }
    }
  }
  int g = lane >> 4, fr = lane & 15;
  if (MODE == 0) {
    // rows are (b*2048+n), cols f = bn*64 + nj*16 + fr; one head per bn (h = bn)
    unsigned short* vt = (unsigned short*)C;
    int growbase = bm * 64 + w * 16 + g * 4;      // 4 consecutive n per lane (r=0..3)
    int b = growbase >> 11;
    int n = growbase & 2047;
#pragma unroll
    for (int nj = 0; nj < 4; ++nj) {
      int d = nj * 16 + fr;
      unsigned short p0 = f2bf(acc[nj][0]), p1 = f2bf(acc[nj][1]);
      unsigned short p2 = f2bf(acc[nj][2]), p3 = f2bf(acc[nj][3]);
      uint2 u;
      u.x = (unsigned)p0 | ((unsigned)p1 << 16);
      u.y = (unsigned)p2 | ((unsigned)p3 << 16);
      *(uint2*)(vt + ((size_t)((b * 16 + bn) * 64 + d)) * 2048 + n) = u;
    }
  } else {
    float* Cf = (float*)C;
    int grow = bm * 64 + w * 16 + g * 4;
#pragma unroll
    for (int nj = 0; nj < 4; ++nj) {
#pragma unroll
      for (int r = 0; r < 4; ++r) {
        Cf[(size_t)(grow + r) * 1024 + bn * 64 + nj * 16 + fr] = acc[nj][r];
      }
    }
  }
}

// ---------------- fused dense attention (flash-style, hid fused in prologue) ----
// Per block: one (b,h), 64 Q rows (qt). 4 waves, wave owns 16 Q rows.
// Prologue: Q = relu(xh @ W1^T + b1) via MFMA, bf16 frags into swizzled Qs.
// Loop over m in steps of 64: S = Q@W2^T + b2 (MFMA), online softmax, O += P@V.
__global__ __launch_bounds__(256) void flash_kernel(const unsigned short* __restrict__ xb,
                                                    const unsigned short* __restrict__ w1b,
                                                    const float* __restrict__ b1,
                                                    const unsigned short* __restrict__ w2b,
                                                    const float* __restrict__ b2,
                                                    const unsigned short* __restrict__ vt,
                                                    unsigned short* __restrict__ aout) {
  __shared__ __attribute__((aligned(16))) char Qs[8192];
  __shared__ __attribute__((aligned(16))) char Ks[8192];
  __shared__ __attribute__((aligned(16))) char Vs[8192];
  __shared__ __attribute__((aligned(16))) char Ps[8192];   // per-wave 2KB P tiles
  int tid = threadIdx.x, w = tid >> 6, lane = tid & 63;
  int qt = blockIdx.x, bh = blockIdx.y;
  int b = bh >> 4, h = bh & 15;
  int g = lane >> 4, fr = lane & 15;

  // ---- prologue: Q = relu(xh @ W1^T + b1) ----
  // stage x tile (rows n=qt*64.., cols h*64..h*64+63) into Qs; W1 into Ps
  stage64((const char*)(xb + ((size_t)(b * 2048 + qt * 64)) * 1024 + h * 64), 2048, Qs, w, lane);
  stage64((const char*)w1b, 128, Ps, w, lane);
  __syncthreads();
  {
    f32x4 hq[4] = {};
#pragma unroll
    for (int kt = 0; kt < 2; ++kt) {
      bf16x8 a = rdfrag(Qs, w * 16 + fr, kt, lane);
#pragma unroll
      for (int j = 0; j < 4; ++j) {
        bf16x8 bw = rdfrag(Ps, j * 16 + fr, kt, lane);
        hq[j] = __builtin_amdgcn_mfma_f32_16x16x32_bf16(a, bw, hq[j], 0, 0, 0);
      }
    }
    // bias + relu, write bf16 frags back into Qs (same swizzle as rdfrag)
#pragma unroll
    for (int r = 0; r < 4; ++r) {
      int row = w * 16 + g * 4 + r;
      int swz = (row & 7) << 4;
#pragma unroll
      for (int j = 0; j < 4; ++j) {
        float v = fmaxf(hq[j][r] + b1[j * 16 + fr], 0.f);
        int byteoff = (row << 7) + ((((j << 4) + fr) << 1) ^ swz);
        *(unsigned short*)(Qs + byteoff) = f2bf(v);
      }
    }
  }
  // per-wave region self-consistent: no cross-wave barrier needed here
  bf16x8 qf0 = rdfrag(Qs, w * 16 + fr, 0, lane);
  bf16x8 qf1 = rdfrag(Qs, w * 16 + fr, 1, lane);

  f32x4 o[4] = {};
  float mrun[4] = {-INFINITY, -INFINITY, -INFINITY, -INFINITY};
  float lrun[4] = {0.f, 0.f, 0.f, 0.f};
  char* myPs = Ps + (w << 11);

  for (int mt = 0; mt < 32; ++mt) {
    __syncthreads();
    stage64((const char*)w2b + (size_t)mt * 8192, 128, Ks, w, lane);
    stage64((const char*)vt + (size_t)bh * 64 * 4096 + (size_t)mt * 128, 4096, Vs, w, lane);
    __syncthreads();

    // S tile: rows = q (D-layout row g*4+r), cols = m local (l&15 per 16-subtile j)
    f32x4 s[4] = {};
#pragma unroll
    for (int j = 0; j < 4; ++j) {
      bf16x8 kb0 = rdfrag(Ks, j * 16 + fr, 0, lane);
      s[j] = __builtin_amdgcn_mfma_f32_16x16x32_bf16(qf0, kb0, s[j], 0, 0, 0);
      bf16x8 kb1 = rdfrag(Ks, j * 16 + fr, 1, lane);
      s[j] = __builtin_amdgcn_mfma_f32_16x16x32_bf16(qf1, kb1, s[j], 0, 0, 0);
    }
#pragma unroll
    for (int j = 0; j < 4; ++j) {
      float bv = b2[mt * 64 + j * 16 + fr];
#pragma unroll
      for (int r = 0; r < 4; ++r) s[j][r] += bv;
    }

    // online softmax per q-row r (row-max across j and the 16 lanes of the group)
#pragma unroll
    for (int r = 0; r < 4; ++r) {
      float mx = fmaxf(fmaxf(s[0][r], s[1][r]), fmaxf(s[2][r], s[3][r]));
      mx = fmaxf(mx, __shfl_xor(mx, 1));
      mx = fmaxf(mx, __shfl_xor(mx, 2));
      mx = fmaxf(mx, __shfl_xor(mx, 4));
      mx = fmaxf(mx, __shfl_xor(mx, 8));
      float mnew = fmaxf(mrun[r], mx);
      float sc = __expf(mrun[r] - mnew);           // exp(-inf)=0 on first tile
      mrun[r] = mnew;
      float ps = 0.f;
#pragma unroll
      for (int j = 0; j < 4; ++j) {
        float p = __expf(s[j][r] - mnew);
        s[j][r] = p;
        ps += p;
      }
      lrun[r] = lrun[r] * sc + ps;                 // per-lane partial row sum
#pragma unroll
      for (int dj = 0; dj < 4; ++dj) o[dj][r] *= sc;
    }

    // P (D-layout) -> bf16 -> per-wave LDS, swizzled to match rdfrag
#pragma unroll
    for (int r = 0; r < 4; ++r) {
      int row = g * 4 + r;
      int swz = (row & 7) << 4;
#pragma unroll
      for (int j = 0; j < 4; ++j) {
        int byteoff = (row << 7) + (((((j << 4) + fr) << 1)) ^ swz);
        *(unsigned short*)(myPs + byteoff) = f2bf(s[j][r]);
      }
    }

    // O += P @ V   (A-frag = P rows q, B-frag = Vt rows d)
#pragma unroll
    for (int kt = 0; kt < 2; ++kt) {
      bf16x8 pf = rdfrag(myPs, fr, kt, lane);
#pragma unroll
      for (int dj = 0; dj < 4; ++dj) {
        bf16x8 vb = rdfrag(Vs, dj * 16 + fr, kt, lane);
        o[dj] = __builtin_amdgcn_mfma_f32_16x16x32_bf16(pf, vb, o[dj], 0, 0, 0);
      }
    }
  }

  // finalize: reduce row sums across the 16-lane group, normalize, store bf16
  float inv[4];
#pragma unroll
  for (int r = 0; r < 4; ++r) {
    float l = lrun[r];
    l += __shfl_xor(l, 1);
    l += __shfl_xor(l, 2);
    l += __shfl_xor(l, 4);
    l += __shfl_xor(l, 8);
    inv[r] = 1.f / l;
  }
  int nbase = qt * 64 + w * 16 + g * 4;
#pragma unroll
  for (int dj = 0; dj < 4; ++dj) {
    int f = h * 64 + dj * 16 + fr;
#pragma unroll
    for (int r = 0; r < 4; ++r) {
      aout[((size_t)(b * 2048 + nbase + r)) * 1024 + f] = f2bf(o[dj][r] * inv[r]);
    }
  }
}

// ---------------- launch ----------------
extern "C" void kernel_launch(void* const* d_in, const int* in_sizes, int n_in,
                              void* d_out, int out_size, void* d_ws, size_t ws_size,
                              hipStream_t stream) {
  (void)in_sizes; (void)n_in; (void)out_size; (void)ws_size;
  const float* x  = (const float*)d_in[0];
  const float* W1 = (const float*)d_in[1];
  const float* b1 = (const float*)d_in[2];
  const float* W2 = (const float*)d_in[3];
  const float* b2 = (const float*)d_in[4];
  const float* Wv = (const float*)d_in[5];
  const float* Wo = (const float*)d_in[6];
  float* out = (float*)d_out;

  char* ws = (char*)d_ws;
  unsigned short* xb   = (unsigned short*)(ws);             // x bf16      8 MB
  unsigned short* wvb  = (unsigned short*)(ws +  8388608);  // Wv bf16     2 MB
  unsigned short* wob  = (unsigned short*)(ws + 10485760);  // Wo bf16     2 MB
  unsigned short* w2b  = (unsigned short*)(ws + 12582912);  // W2 bf16   256 KB
  unsigned short* w1b  = (unsigned short*)(ws + 12845056);  // W1 bf16     8 KB
  unsigned short* vt   = (unsigned short*)(ws + 21233664);  // V^T bf16    8 MB
  unsigned short* aout = (unsigned short*)(ws + 29622272);  // out_h bf16  8 MB
  // total ws usage: 38,010,880 bytes

  conv_bf16<<<1024, 256, 0, stream>>>(x,  xb,  4194304 / 4);
  conv_bf16<<<1024, 256, 0, stream>>>(Wv, wvb, 1048576 / 4);
  conv_bf16<<<1024, 256, 0, stream>>>(Wo, wob, 1048576 / 4);
  conv_bf16<<< 128, 256, 0, stream>>>(W2, w2b,  131072 / 4);
  conv_bf16<<<   4, 256, 0, stream>>>(W1, w1b,    4096 / 4);

  // value = x @ Wv^T -> vt[bh][d][m]
  gemm_bt<0><<<dim3(64, 16), 256, 0, stream>>>(xb, wvb, (void*)vt, 1024);
  // fused: Q = relu(xh@W1^T+b1); softmax(Q @ W2^T + b2) @ V -> aout (merged heads)
  flash_kernel<<<dim3(32, 32), 256, 0, stream>>>(xb, w1b, b1, w2b, b2, vt, aout);
  // out = aout @ Wo^T (fp32)
  gemm_bt<1><<<dim3(64, 16), 256, 0, stream>>>(aout, wob, (void*)out, 1024);
}

// Round 3
// 136.002 us; speedup vs baseline: 1.9825x; 1.0860x over previous
//
#include <hip/hip_runtime.h>
#include <hip/hip_bf16.h>
#include <math.h>
#include <stdint.h>

// MultiHeadDenseAttention: B=2, H=16, N=2048, D=64, F=1024, M=2048
//  value = x @ Wv^T                  (GEMM, writes V^T per head: vt[bh][d][m])
//  hid   = relu(xh @ W1^T + b1)      (fused into flash prologue, MFMA)
//  attn  = softmax(hid @ W2^T + b2)  (flash, swapped-QK^T, no-max softmax)
//  out_h = attn @ vh                 (fused with above)
//  out   = merge(out_h) @ Wo^T       (GEMM, fp32 out)

typedef __attribute__((ext_vector_type(8))) short bf16x8;
typedef __attribute__((ext_vector_type(4))) float f32x4;

__device__ __forceinline__ unsigned short f2bf(float f) {
  union { float f; unsigned u; } v; v.f = f;
  unsigned r = v.u + 0x7FFFu + ((v.u >> 16) & 1u);   // round-to-nearest-even
  return (unsigned short)(r >> 16);
}

// ---------------- fp32 -> bf16 convert ----------------
__global__ __launch_bounds__(256) void conv_bf16(const float* __restrict__ src,
                                                 unsigned short* __restrict__ dst, int nq) {
  int stride = gridDim.x * blockDim.x;
  for (int q = blockIdx.x * blockDim.x + threadIdx.x; q < nq; q += stride) {
    float4 v = *(const float4*)(src + (size_t)q * 4);
    unsigned short p0 = f2bf(v.x), p1 = f2bf(v.y), p2 = f2bf(v.z), p3 = f2bf(v.w);
    uint2 u;
    u.x = (unsigned)p0 | ((unsigned)p1 << 16);
    u.y = (unsigned)p2 | ((unsigned)p3 << 16);
    *(uint2*)(dst + (size_t)q * 4) = u;
  }
}

// ---------------- exp table for b2 ----------------
__global__ __launch_bounds__(256) void exp_kernel(const float* __restrict__ src,
                                                  float* __restrict__ dst, int n) {
  int i = blockIdx.x * blockDim.x + threadIdx.x;
  if (i < n) dst[i] = __expf(src[i]);
}

// ---------------- shared staging/frag helpers ----------------
// Stage a 64-row x 128-byte tile into 8KB of LDS via global_load_lds.
// LDS(row, chunk c') holds global chunk c' ^ (row&7)  (XOR swizzle via source addr).
__device__ __forceinline__ void stage64(const char* g, size_t ldbytes, char* lds,
                                        int w, int lane) {
#pragma unroll
  for (int t = 0; t < 2; ++t) {
    int row  = w * 16 + t * 8 + (lane >> 3);      // row & 7 == lane>>3
    int csrc = (lane & 7) ^ (lane >> 3);          // inverse-swizzled source chunk
    const char* src = g + (size_t)row * ldbytes + (csrc << 4);
    char* dst = lds + ((w * 2 + t) << 10);        // wave-uniform base; HW adds lane*16
    __builtin_amdgcn_global_load_lds((const __attribute__((address_space(1))) void*)src,
                                     (__attribute__((address_space(3))) void*)dst,
                                     16, 0, 0);
  }
}

// Read an MFMA 16x16x32 operand fragment (8 bf16, k-contiguous) from a staged tile.
__device__ __forceinline__ bf16x8 rdfrag(const char* lds, int row, int kt, int lane) {
  int c = ((kt << 2) + (lane >> 4)) ^ (row & 7);
  return *(const bf16x8*)(lds + row * 128 + (c << 4));
}

// ---------------- GEMM: C = A @ B^T, A[M][K] bf16, B[N][K] bf16 ----------------
// MODE 0: store bf16 transposed-per-head into vt[bh*64+d][2048] (value projection)
// MODE 1: store fp32 row-major [M][1024] (final output)
template<int MODE>
__global__ __launch_bounds__(256) void gemm_bt(const unsigned short* __restrict__ A,
                                               const unsigned short* __restrict__ B,
                                               void* __restrict__ C, int K) {
  __shared__ __attribute__((aligned(16))) char As[8192];
  __shared__ __attribute__((aligned(16))) char Bs[8192];
  int tid = threadIdx.x, w = tid >> 6, lane = tid & 63;
  int bm = blockIdx.x, bn = blockIdx.y;
  const char* Ab = (const char*)A + (size_t)bm * 64 * (K * 2);
  const char* Bb = (const char*)B + (size_t)bn * 64 * (K * 2);
  f32x4 acc[4] = {};
  int nsteps = K >> 6;
  for (int kk = 0; kk < nsteps; ++kk) {
    __syncthreads();
    stage64(Ab + (size_t)kk * 128, (size_t)K * 2, As, w, lane);
    stage64(Bb + (size_t)kk * 128, (size_t)K * 2, Bs, w, lane);
    __syncthreads();
#pragma unroll
    for (int kt = 0; kt < 2; ++kt) {
      bf16x8 a = rdfrag(As, w * 16 + (lane & 15), kt, lane);
#pragma unroll
      for (int nj = 0; nj < 4; ++nj) {
        bf16x8 b = rdfrag(Bs, nj * 16 + (lane & 15), kt, lane);
        acc[nj] = __builtin_amdgcn_mfma_f32_16x16x32_bf16(a, b, acc[nj], 0, 0, 0);
      }
    }
  }
  int g = lane >> 4, fr = lane & 15;
  if (MODE == 0) {
    unsigned short* vt = (unsigned short*)C;
    int growbase = bm * 64 + w * 16 + g * 4;
    int b = growbase >> 11;
    int n = growbase & 2047;
#pragma unroll
    for (int nj = 0; nj < 4; ++nj) {
      int d = nj * 16 + fr;
      unsigned short p0 = f2bf(acc[nj][0]), p1 = f2bf(acc[nj][1]);
      unsigned short p2 = f2bf(acc[nj][2]), p3 = f2bf(acc[nj][3]);
      uint2 u;
      u.x = (unsigned)p0 | ((unsigned)p1 << 16);
      u.y = (unsigned)p2 | ((unsigned)p3 << 16);
      *(uint2*)(vt + ((size_t)((b * 16 + bn) * 64 + d)) * 2048 + n) = u;
    }
  } else {
    float* Cf = (float*)C;
    int grow = bm * 64 + w * 16 + g * 4;
#pragma unroll
    for (int nj = 0; nj < 4; ++nj) {
#pragma unroll
      for (int r = 0; r < 4; ++r) {
        Cf[(size_t)(grow + r) * 1024 + bn * 64 + nj * 16 + fr] = acc[nj][r];
      }
    }
  }
}

// ---------------- fused dense attention ----------------
// Per block: one (b,h), 64 Q rows. 4 waves; wave owns 16 q rows.
// Swapped QK^T: lane holds S[q=fr][m=mt*64+j*16+g*4+r] -> softmax lane-local.
// No max-subtraction (|logits| ~ O(1) for this op; exact after normalization).
// 2-phase double-buffered K/V staging: one barrier per m-step.
__global__ __launch_bounds__(256) void flash_kernel(const unsigned short* __restrict__ xb,
                                                    const unsigned short* __restrict__ w1b,
                                                    const float* __restrict__ b1,
                                                    const unsigned short* __restrict__ w2b,
                                                    const float* __restrict__ eb2,
                                                    const unsigned short* __restrict__ vt,
                                                    unsigned short* __restrict__ aout) {
  __shared__ __attribute__((aligned(16))) char Ks[2][8192];
  __shared__ __attribute__((aligned(16))) char Vs[2][8192];
  __shared__ __attribute__((aligned(16))) char Qs[8192];   // x-tile/Q frags, then P tiles
  int tid = threadIdx.x, w = tid >> 6, lane = tid & 63;
  int qt = blockIdx.x, bh = blockIdx.y;
  int b = bh >> 4, h = bh & 15;
  int g = lane >> 4, fr = lane & 15;

  // ---- prologue: Q = relu(xh @ W1^T + b1) (x -> Ks[0], W1 -> Vs[0]) ----
  stage64((const char*)(xb + ((size_t)(b * 2048 + qt * 64)) * 1024 + h * 64), 2048, Ks[0], w, lane);
  stage64((const char*)w1b, 128, Vs[0], w, lane);
  __syncthreads();
  {
    f32x4 hq[4] = {};
#pragma unroll
    for (int kt = 0; kt < 2; ++kt) {
      bf16x8 a = rdfrag(Ks[0], w * 16 + fr, kt, lane);
#pragma unroll
      for (int j = 0; j < 4; ++j) {
        bf16x8 bw = rdfrag(Vs[0], j * 16 + fr, kt, lane);
        hq[j] = __builtin_amdgcn_mfma_f32_16x16x32_bf16(a, bw, hq[j], 0, 0, 0);
      }
    }
#pragma unroll
    for (int r = 0; r < 4; ++r) {
      int row = w * 16 + g * 4 + r;
      int swz = (row & 7) << 4;
#pragma unroll
      for (int j = 0; j < 4; ++j) {
        float v = fmaxf(hq[j][r] + b1[j * 16 + fr], 0.f);
        int byteoff = (row << 7) + ((((j << 4) + fr) << 1) ^ swz);
        *(unsigned short*)(Qs + byteoff) = f2bf(v);
      }
    }
  }
  bf16x8 qf0 = rdfrag(Qs, w * 16 + fr, 0, lane);   // own-wave rows: no barrier needed
  bf16x8 qf1 = rdfrag(Qs, w * 16 + fr, 1, lane);
  __syncthreads();                                  // all waves done with Ks[0]/Vs[0]

  // ---- pipelined m-loop ----
  const char* vtb = (const char*)vt + (size_t)bh * 64 * 4096;
  stage64((const char*)w2b, 128, Ks[0], w, lane);
  stage64(vtb, 4096, Vs[0], w, lane);

  f32x4 o[4] = {};
  float lrun = 0.f;
  char* myPs = Qs + (w << 11);                      // wave's own 16 rows region
  int cur = 0;
  __syncthreads();                                  // implicit vmcnt(0): tile 0 ready

  for (int mt = 0; mt < 32; ++mt) {
    if (mt < 31) {                                  // issue next tile's loads first
      stage64((const char*)w2b + (size_t)(mt + 1) * 8192, 128, Ks[cur ^ 1], w, lane);
      stage64(vtb + (size_t)(mt + 1) * 128, 4096, Vs[cur ^ 1], w, lane);
    }

    // S^T: mfma(K,Q) -> D[col=q=fr][row=m local j*16+g*4+r]
    f32x4 s[4] = {};
#pragma unroll
    for (int j = 0; j < 4; ++j) {
      bf16x8 kb0 = rdfrag(Ks[cur], j * 16 + fr, 0, lane);
      s[j] = __builtin_amdgcn_mfma_f32_16x16x32_bf16(kb0, qf0, s[j], 0, 0, 0);
      bf16x8 kb1 = rdfrag(Ks[cur], j * 16 + fr, 1, lane);
      s[j] = __builtin_amdgcn_mfma_f32_16x16x32_bf16(kb1, qf1, s[j], 0, 0, 0);
    }

    // p = exp(s) * exp(b2[m]); accumulate per-lane row partial sum
    int swz = (fr & 7) << 4;
#pragma unroll
    for (int j = 0; j < 4; ++j) {
      float4 e4 = *(const float4*)(eb2 + mt * 64 + j * 16 + g * 4);
      float p0 = __expf(s[j][0]) * e4.x;
      float p1 = __expf(s[j][1]) * e4.y;
      float p2 = __expf(s[j][2]) * e4.z;
      float p3 = __expf(s[j][3]) * e4.w;
      lrun += (p0 + p1) + (p2 + p3);
      uint2 u;
      u.x = (unsigned)f2bf(p0) | ((unsigned)f2bf(p1) << 16);
      u.y = (unsigned)f2bf(p2) | ((unsigned)f2bf(p3) << 16);
      int byteoff = (fr << 7) + ((((j << 5) + (g << 3))) ^ swz);
      *(uint2*)(myPs + byteoff) = u;                // 4 m-consecutive bf16, 8B write
    }

    // O += P @ V  (A-frag = P rows q, B-frag = Vt rows d)
#pragma unroll
    for (int kt = 0; kt < 2; ++kt) {
      bf16x8 pf = rdfrag(myPs, fr, kt, lane);
#pragma unroll
      for (int dj = 0; dj < 4; ++dj) {
        bf16x8 vb = rdfrag(Vs[cur], dj * 16 + fr, kt, lane);
        o[dj] = __builtin_amdgcn_mfma_f32_16x16x32_bf16(pf, vb, o[dj], 0, 0, 0);
      }
    }
    __syncthreads();                                // next tile landed; all done w/ cur
    cur ^= 1;
  }

  // ---- finalize: full row sums (q=fr), normalize, store bf16 ----
  lrun += __shfl_xor(lrun, 16);
  lrun += __shfl_xor(lrun, 32);
  float inv = 1.f / lrun;
  float invr[4];
#pragma unroll
  for (int r = 0; r < 4; ++r) invr[r] = __shfl(inv, g * 4 + r);   // inv for q=g*4+r
  int nbase = qt * 64 + w * 16 + g * 4;
#pragma unroll
  for (int dj = 0; dj < 4; ++dj) {
    int f = h * 64 + dj * 16 + fr;
#pragma unroll
    for (int r = 0; r < 4; ++r) {
      aout[((size_t)(b * 2048 + nbase + r)) * 1024 + f] = f2bf(o[dj][r] * invr[r]);
    }
  }
}

// ---------------- launch ----------------
extern "C" void kernel_launch(void* const* d_in, const int* in_sizes, int n_in,
                              void* d_out, int out_size, void* d_ws, size_t ws_size,
                              hipStream_t stream) {
  (void)in_sizes; (void)n_in; (void)out_size; (void)ws_size;
  const float* x  = (const float*)d_in[0];
  const float* W1 = (const float*)d_in[1];
  const float* b1 = (const float*)d_in[2];
  const float* W2 = (const float*)d_in[3];
  const float* b2 = (const float*)d_in[4];
  const float* Wv = (const float*)d_in[5];
  const float* Wo = (const float*)d_in[6];
  float* out = (float*)d_out;

  char* ws = (char*)d_ws;
  unsigned short* xb   = (unsigned short*)(ws);             // x bf16      8 MB
  unsigned short* wvb  = (unsigned short*)(ws +  8388608);  // Wv bf16     2 MB
  unsigned short* wob  = (unsigned short*)(ws + 10485760);  // Wo bf16     2 MB
  unsigned short* w2b  = (unsigned short*)(ws + 12582912);  // W2 bf16   256 KB
  unsigned short* w1b  = (unsigned short*)(ws + 12845056);  // W1 bf16     8 KB
  float*          eb2  = (float*)         (ws + 12853248);  // exp(b2)     8 KB
  unsigned short* vt   = (unsigned short*)(ws + 21233664);  // V^T bf16    8 MB
  unsigned short* aout = (unsigned short*)(ws + 29622272);  // out_h bf16  8 MB

  conv_bf16<<<1024, 256, 0, stream>>>(x,  xb,  4194304 / 4);
  conv_bf16<<<1024, 256, 0, stream>>>(Wv, wvb, 1048576 / 4);
  conv_bf16<<<1024, 256, 0, stream>>>(Wo, wob, 1048576 / 4);
  conv_bf16<<< 128, 256, 0, stream>>>(W2, w2b,  131072 / 4);
  conv_bf16<<<   4, 256, 0, stream>>>(W1, w1b,    4096 / 4);
  exp_kernel<<<   8, 256, 0, stream>>>(b2, eb2, 2048);

  // value = x @ Wv^T -> vt[bh][d][m]
  gemm_bt<0><<<dim3(64, 16), 256, 0, stream>>>(xb, wvb, (void*)vt, 1024);
  // fused: Q = relu(xh@W1^T+b1); softmax(Q@W2^T + b2) @ V -> aout (merged heads)
  flash_kernel<<<dim3(32, 32), 256, 0, stream>>>(xb, w1b, b1, w2b, eb2, vt, aout);
  // out = aout @ Wo^T (fp32)
  gemm_bt<1><<<dim3(64, 16), 256, 0, stream>>>(aout, wob, (void*)out, 1024);
}

// Round 4
// 113.719 us; speedup vs baseline: 2.3709x; 1.1959x over previous
//
#include <hip/hip_runtime.h>
#include <hip/hip_bf16.h>
#include <math.h>
#include <stdint.h>

// MultiHeadDenseAttention: B=2, H=16, N=2048, D=64, F=1024, M=2048
//  value = x @ Wv^T                  (GEMM, writes V^T per head: vt[bh][d][m])
//  hid   = relu(xh @ W1^T + b1)      (fused into flash prologue, MFMA)
//  attn  = softmax(hid @ W2^T + b2)  (flash, swapped-QK^T, exp2-domain, no-max)
//  out_h = attn @ vh                 (fused with above)
//  out   = merge(out_h) @ Wo^T       (GEMM, fp32 out)

typedef __attribute__((ext_vector_type(8))) short bf16x8;
typedef __attribute__((ext_vector_type(4))) float f32x4;

#define LOG2E 1.4426950408889634f

__device__ __forceinline__ unsigned short f2bf(float f) {
  union { float f; unsigned u; } v; v.f = f;
  unsigned r = v.u + 0x7FFFu + ((v.u >> 16) & 1u);   // round-to-nearest-even
  return (unsigned short)(r >> 16);
}

// ---------------- fp32 -> bf16 convert ----------------
__global__ __launch_bounds__(256) void conv_bf16(const float* __restrict__ src,
                                                 unsigned short* __restrict__ dst, int nq) {
  int stride = gridDim.x * blockDim.x;
  for (int q = blockIdx.x * blockDim.x + threadIdx.x; q < nq; q += stride) {
    float4 v = *(const float4*)(src + (size_t)q * 4);
    unsigned short p0 = f2bf(v.x), p1 = f2bf(v.y), p2 = f2bf(v.z), p3 = f2bf(v.w);
    uint2 u;
    u.x = (unsigned)p0 | ((unsigned)p1 << 16);
    u.y = (unsigned)p2 | ((unsigned)p3 << 16);
    *(uint2*)(dst + (size_t)q * 4) = u;
  }
}

// ---------------- b2 * log2(e) table ----------------
__global__ __launch_bounds__(256) void b2l_kernel(const float* __restrict__ src,
                                                  float* __restrict__ dst, int n) {
  int i = blockIdx.x * blockDim.x + threadIdx.x;
  if (i < n) dst[i] = src[i] * LOG2E;
}

// ---------------- shared staging/frag helpers ----------------
// Stage a 64-row x 128-byte tile into 8KB of LDS via global_load_lds.
// LDS(row, chunk c') holds global chunk c' ^ (row&7)  (XOR swizzle via source addr).
__device__ __forceinline__ void stage64(const char* g, size_t ldbytes, char* lds,
                                        int w, int lane) {
#pragma unroll
  for (int t = 0; t < 2; ++t) {
    int row  = w * 16 + t * 8 + (lane >> 3);      // row & 7 == lane>>3
    int csrc = (lane & 7) ^ (lane >> 3);          // inverse-swizzled source chunk
    const char* src = g + (size_t)row * ldbytes + (csrc << 4);
    char* dst = lds + ((w * 2 + t) << 10);        // wave-uniform base; HW adds lane*16
    __builtin_amdgcn_global_load_lds((const __attribute__((address_space(1))) void*)src,
                                     (__attribute__((address_space(3))) void*)dst,
                                     16, 0, 0);
  }
}

// Read an MFMA 16x16x32 operand fragment (8 bf16, k-contiguous) from a staged tile.
__device__ __forceinline__ bf16x8 rdfrag(const char* lds, int row, int kt, int lane) {
  int c = ((kt << 2) + (lane >> 4)) ^ (row & 7);
  return *(const bf16x8*)(lds + row * 128 + (c << 4));
}

// ---------------- GEMM: C = A @ B^T, A[M][K] bf16, B[N][K] bf16 ----------------
// MODE 0: store bf16 transposed-per-head into vt[bh*64+d][2048] (value projection)
// MODE 1: store fp32 row-major [M][1024] (final output)
template<int MODE>
__global__ __launch_bounds__(256) void gemm_bt(const unsigned short* __restrict__ A,
                                               const unsigned short* __restrict__ B,
                                               void* __restrict__ C, int K) {
  __shared__ __attribute__((aligned(16))) char As[8192];
  __shared__ __attribute__((aligned(16))) char Bs[8192];
  int tid = threadIdx.x, w = tid >> 6, lane = tid & 63;
  int bm = blockIdx.x, bn = blockIdx.y;
  const char* Ab = (const char*)A + (size_t)bm * 64 * (K * 2);
  const char* Bb = (const char*)B + (size_t)bn * 64 * (K * 2);
  f32x4 acc[4] = {};
  int nsteps = K >> 6;
  for (int kk = 0; kk < nsteps; ++kk) {
    __syncthreads();
    stage64(Ab + (size_t)kk * 128, (size_t)K * 2, As, w, lane);
    stage64(Bb + (size_t)kk * 128, (size_t)K * 2, Bs, w, lane);
    __syncthreads();
#pragma unroll
    for (int kt = 0; kt < 2; ++kt) {
      bf16x8 a = rdfrag(As, w * 16 + (lane & 15), kt, lane);
#pragma unroll
      for (int nj = 0; nj < 4; ++nj) {
        bf16x8 b = rdfrag(Bs, nj * 16 + (lane & 15), kt, lane);
        acc[nj] = __builtin_amdgcn_mfma_f32_16x16x32_bf16(a, b, acc[nj], 0, 0, 0);
      }
    }
  }
  int g = lane >> 4, fr = lane & 15;
  if (MODE == 0) {
    unsigned short* vt = (unsigned short*)C;
    int growbase = bm * 64 + w * 16 + g * 4;
    int b = growbase >> 11;
    int n = growbase & 2047;
#pragma unroll
    for (int nj = 0; nj < 4; ++nj) {
      int d = nj * 16 + fr;
      unsigned short p0 = f2bf(acc[nj][0]), p1 = f2bf(acc[nj][1]);
      unsigned short p2 = f2bf(acc[nj][2]), p3 = f2bf(acc[nj][3]);
      uint2 u;
      u.x = (unsigned)p0 | ((unsigned)p1 << 16);
      u.y = (unsigned)p2 | ((unsigned)p3 << 16);
      *(uint2*)(vt + ((size_t)((b * 16 + bn) * 64 + d)) * 2048 + n) = u;
    }
  } else {
    float* Cf = (float*)C;
    int grow = bm * 64 + w * 16 + g * 4;
#pragma unroll
    for (int nj = 0; nj < 4; ++nj) {
#pragma unroll
      for (int r = 0; r < 4; ++r) {
        Cf[(size_t)(grow + r) * 1024 + bn * 64 + nj * 16 + fr] = acc[nj][r];
      }
    }
  }
}

// ---------------- fused dense attention ----------------
// Per block: one (b,h), 64 Q rows. 4 waves; wave owns 16 q rows.
// Swapped QK^T: lane holds S[q=fr][m]; bias folded into MFMA C-init (log2 domain);
// p = v_exp_f32(s) directly (Q pre-scaled by log2e). Row sums via ones-MFMA.
// 2-phase double-buffered K/V staging: one barrier per m-step.
__global__ __launch_bounds__(256) void flash_kernel(const unsigned short* __restrict__ xb,
                                                    const unsigned short* __restrict__ w1b,
                                                    const float* __restrict__ b1,
                                                    const unsigned short* __restrict__ w2b,
                                                    const float* __restrict__ b2l,
                                                    const unsigned short* __restrict__ vt,
                                                    unsigned short* __restrict__ aout) {
  __shared__ __attribute__((aligned(16))) char Ks[2][8192];
  __shared__ __attribute__((aligned(16))) char Vs[2][8192];
  __shared__ __attribute__((aligned(16))) char Qs[8192];   // x-tile/Q frags, then P tiles
  int tid = threadIdx.x, w = tid >> 6, lane = tid & 63;
  int qt = blockIdx.x, bh = blockIdx.y;
  int b = bh >> 4, h = bh & 15;
  int g = lane >> 4, fr = lane & 15;

  // ---- prologue: Q = relu(xh @ W1^T + b1) * log2e  (x -> Ks[0], W1 -> Vs[0]) ----
  stage64((const char*)(xb + ((size_t)(b * 2048 + qt * 64)) * 1024 + h * 64), 2048, Ks[0], w, lane);
  stage64((const char*)w1b, 128, Vs[0], w, lane);
  __syncthreads();
  {
    f32x4 hq[4] = {};
#pragma unroll
    for (int kt = 0; kt < 2; ++kt) {
      bf16x8 a = rdfrag(Ks[0], w * 16 + fr, kt, lane);
#pragma unroll
      for (int j = 0; j < 4; ++j) {
        bf16x8 bw = rdfrag(Vs[0], j * 16 + fr, kt, lane);
        hq[j] = __builtin_amdgcn_mfma_f32_16x16x32_bf16(a, bw, hq[j], 0, 0, 0);
      }
    }
#pragma unroll
    for (int r = 0; r < 4; ++r) {
      int row = w * 16 + g * 4 + r;
      int swz = (row & 7) << 4;
#pragma unroll
      for (int j = 0; j < 4; ++j) {
        float v = fmaxf(hq[j][r] + b1[j * 16 + fr], 0.f) * LOG2E;
        int byteoff = (row << 7) + ((((j << 4) + fr) << 1) ^ swz);
        *(unsigned short*)(Qs + byteoff) = f2bf(v);
      }
    }
  }
  bf16x8 qf0 = rdfrag(Qs, w * 16 + fr, 0, lane);   // own-wave rows: no barrier needed
  bf16x8 qf1 = rdfrag(Qs, w * 16 + fr, 1, lane);
  __syncthreads();                                  // all waves done with Ks[0]/Vs[0]

  // ---- pipelined m-loop ----
  const char* vtb = (const char*)vt + (size_t)bh * 64 * 4096;
  stage64((const char*)w2b, 128, Ks[0], w, lane);
  stage64(vtb, 4096, Vs[0], w, lane);

  bf16x8 ones;
#pragma unroll
  for (int i = 0; i < 8; ++i) ones[i] = (short)0x3F80;   // bf16 1.0

  f32x4 o[4] = {};
  f32x4 o1 = {};                                    // row sums of P (per q=g*4+r)
  char* myPs = Qs + (w << 11);                      // wave's own 16 rows region
  int cur = 0;
  int swz = (fr & 7) << 4;

  float4 e4a[4];                                    // prefetched bias (log2 domain)
#pragma unroll
  for (int j = 0; j < 4; ++j) e4a[j] = *(const float4*)(b2l + j * 16 + g * 4);

  __syncthreads();                                  // implicit vmcnt(0): tile 0 ready

  for (int mt = 0; mt < 32; ++mt) {
    if (mt < 31) {                                  // issue next tile's loads first
      stage64((const char*)w2b + (size_t)(mt + 1) * 8192, 128, Ks[cur ^ 1], w, lane);
      stage64(vtb + (size_t)(mt + 1) * 128, 4096, Vs[cur ^ 1], w, lane);
    }

    // S^T: mfma(K,Q), C-init = bias -> s = (logit+b2)*log2e
    f32x4 s[4];
#pragma unroll
    for (int j = 0; j < 4; ++j) {
      s[j] = (f32x4){e4a[j].x, e4a[j].y, e4a[j].z, e4a[j].w};
      bf16x8 kb0 = rdfrag(Ks[cur], j * 16 + fr, 0, lane);
      s[j] = __builtin_amdgcn_mfma_f32_16x16x32_bf16(kb0, qf0, s[j], 0, 0, 0);
      bf16x8 kb1 = rdfrag(Ks[cur], j * 16 + fr, 1, lane);
      s[j] = __builtin_amdgcn_mfma_f32_16x16x32_bf16(kb1, qf1, s[j], 0, 0, 0);
    }
    if (mt < 31) {
#pragma unroll
      for (int j = 0; j < 4; ++j)
        e4a[j] = *(const float4*)(b2l + (mt + 1) * 64 + j * 16 + g * 4);
    }

    // p = 2^s, pack to bf16 pairs, store to P tile
#pragma unroll
    for (int j = 0; j < 4; ++j) {
      float p0, p1, p2, p3;
      asm("v_exp_f32 %0, %1" : "=v"(p0) : "v"(s[j][0]));
      asm("v_exp_f32 %0, %1" : "=v"(p1) : "v"(s[j][1]));
      asm("v_exp_f32 %0, %1" : "=v"(p2) : "v"(s[j][2]));
      asm("v_exp_f32 %0, %1" : "=v"(p3) : "v"(s[j][3]));
      unsigned ux, uy;
      asm("v_cvt_pk_bf16_f32 %0, %1, %2" : "=v"(ux) : "v"(p0), "v"(p1));
      asm("v_cvt_pk_bf16_f32 %0, %1, %2" : "=v"(uy) : "v"(p2), "v"(p3));
      uint2 u; u.x = ux; u.y = uy;
      int byteoff = (fr << 7) + (((j << 5) + (g << 3)) ^ swz);
      *(uint2*)(myPs + byteoff) = u;                // 4 m-consecutive bf16, 8B write
    }

    // O += P @ V ; row sums via ones-MFMA
#pragma unroll
    for (int kt = 0; kt < 2; ++kt) {
      bf16x8 pf = rdfrag(myPs, fr, kt, lane);
      o1 = __builtin_amdgcn_mfma_f32_16x16x32_bf16(pf, ones, o1, 0, 0, 0);
#pragma unroll
      for (int dj = 0; dj < 4; ++dj) {
        bf16x8 vb = rdfrag(Vs[cur], dj * 16 + fr, kt, lane);
        o[dj] = __builtin_amdgcn_mfma_f32_16x16x32_bf16(pf, vb, o[dj], 0, 0, 0);
      }
    }
    __syncthreads();                                // next tile landed; all done w/ cur
    cur ^= 1;
  }

  // ---- finalize: normalize (o1[r] = rowsum for q=g*4+r), store bf16 ----
  float invr[4];
#pragma unroll
  for (int r = 0; r < 4; ++r) invr[r] = 1.f / o1[r];
  int nbase = qt * 64 + w * 16 + g * 4;
#pragma unroll
  for (int dj = 0; dj < 4; ++dj) {
    int f = h * 64 + dj * 16 + fr;
#pragma unroll
    for (int r = 0; r < 4; ++r) {
      aout[((size_t)(b * 2048 + nbase + r)) * 1024 + f] = f2bf(o[dj][r] * invr[r]);
    }
  }
}

// ---------------- launch ----------------
extern "C" void kernel_launch(void* const* d_in, const int* in_sizes, int n_in,
                              void* d_out, int out_size, void* d_ws, size_t ws_size,
                              hipStream_t stream) {
  (void)in_sizes; (void)n_in; (void)out_size; (void)ws_size;
  const float* x  = (const float*)d_in[0];
  const float* W1 = (const float*)d_in[1];
  const float* b1 = (const float*)d_in[2];
  const float* W2 = (const float*)d_in[3];
  const float* b2 = (const float*)d_in[4];
  const float* Wv = (const float*)d_in[5];
  const float* Wo = (const float*)d_in[6];
  float* out = (float*)d_out;

  char* ws = (char*)d_ws;
  unsigned short* xb   = (unsigned short*)(ws);             // x bf16      8 MB
  unsigned short* wvb  = (unsigned short*)(ws +  8388608);  // Wv bf16     2 MB
  unsigned short* wob  = (unsigned short*)(ws + 10485760);  // Wo bf16     2 MB
  unsigned short* w2b  = (unsigned short*)(ws + 12582912);  // W2 bf16   256 KB
  unsigned short* w1b  = (unsigned short*)(ws + 12845056);  // W1 bf16     8 KB
  float*          b2l  = (float*)         (ws + 12853248);  // b2*log2e    8 KB
  unsigned short* vt   = (unsigned short*)(ws + 21233664);  // V^T bf16    8 MB
  unsigned short* aout = (unsigned short*)(ws + 29622272);  // out_h bf16  8 MB

  conv_bf16<<<1024, 256, 0, stream>>>(x,  xb,  4194304 / 4);
  conv_bf16<<<1024, 256, 0, stream>>>(Wv, wvb, 1048576 / 4);
  conv_bf16<<<1024, 256, 0, stream>>>(Wo, wob, 1048576 / 4);
  conv_bf16<<< 128, 256, 0, stream>>>(W2, w2b,  131072 / 4);
  conv_bf16<<<   4, 256, 0, stream>>>(W1, w1b,    4096 / 4);
  b2l_kernel<<<   8, 256, 0, stream>>>(b2, b2l, 2048);

  // value = x @ Wv^T -> vt[bh][d][m]
  gemm_bt<0><<<dim3(64, 16), 256, 0, stream>>>(xb, wvb, (void*)vt, 1024);
  // fused: Q = relu(xh@W1^T+b1); softmax(Q@W2^T + b2) @ V -> aout (merged heads)
  flash_kernel<<<dim3(32, 32), 256, 0, stream>>>(xb, w1b, b1, w2b, b2l, vt, aout);
  // out = aout @ Wo^T (fp32)
  gemm_bt<1><<<dim3(64, 16), 256, 0, stream>>>(aout, wob, (void*)out, 1024);
}

// Round 5
// 110.705 us; speedup vs baseline: 2.4355x; 1.0272x over previous
//
#include <hip/hip_runtime.h>
#include <hip/hip_bf16.h>
#include <math.h>
#include <stdint.h>

// MultiHeadDenseAttention: B=2, H=16, N=2048, D=64, F=1024, M=2048
//  value = x @ Wv^T                  (GEMM, writes V^T per head: vt[bh][d][m])
//  hid   = relu(xh @ W1^T + b1)      (fused into flash prologue, MFMA 32x32)
//  attn  = softmax(hid @ W2^T + b2)  (flash, swapped-QK^T 32x32, exp2, no-max)
//  out_h = attn @ vh                 (fused, P in-register via cvt_pk+permlane)
//  out   = merge(out_h) @ Wo^T       (GEMM, fp32 out)

typedef __attribute__((ext_vector_type(8))) short bf16x8;
typedef __attribute__((ext_vector_type(4))) float f32x4;
typedef __attribute__((ext_vector_type(16))) float f32x16;

#define LOG2E 1.4426950408889634f

__device__ __forceinline__ unsigned short f2bf(float f) {
  union { float f; unsigned u; } v; v.f = f;
  unsigned r = v.u + 0x7FFFu + ((v.u >> 16) & 1u);   // round-to-nearest-even
  return (unsigned short)(r >> 16);
}

// ---------------- fp32 -> bf16 convert ----------------
__global__ __launch_bounds__(256) void conv_bf16(const float* __restrict__ src,
                                                 unsigned short* __restrict__ dst, int nq) {
  int stride = gridDim.x * blockDim.x;
  for (int q = blockIdx.x * blockDim.x + threadIdx.x; q < nq; q += stride) {
    float4 v = *(const float4*)(src + (size_t)q * 4);
    unsigned short p0 = f2bf(v.x), p1 = f2bf(v.y), p2 = f2bf(v.z), p3 = f2bf(v.w);
    uint2 u;
    u.x = (unsigned)p0 | ((unsigned)p1 << 16);
    u.y = (unsigned)p2 | ((unsigned)p3 << 16);
    *(uint2*)(dst + (size_t)q * 4) = u;
  }
}

// ---------------- b2 * log2(e) table ----------------
__global__ __launch_bounds__(256) void b2l_kernel(const float* __restrict__ src,
                                                  float* __restrict__ dst, int n) {
  int i = blockIdx.x * blockDim.x + threadIdx.x;
  if (i < n) dst[i] = src[i] * LOG2E;
}

// ---------------- shared staging/frag helpers ----------------
// Stage a 64-row x 128-byte tile into 8KB of LDS via global_load_lds.
// LDS(row, chunk c') holds global chunk c' ^ (row&7)  (XOR swizzle via source addr).
__device__ __forceinline__ void stage64(const char* g, size_t ldbytes, char* lds,
                                        int w, int lane) {
#pragma unroll
  for (int t = 0; t < 2; ++t) {
    int row  = w * 16 + t * 8 + (lane >> 3);      // row & 7 == lane>>3
    int csrc = (lane & 7) ^ (lane >> 3);          // inverse-swizzled source chunk
    const char* src = g + (size_t)row * ldbytes + (csrc << 4);
    char* dst = lds + ((w * 2 + t) << 10);        // wave-uniform base; HW adds lane*16
    __builtin_amdgcn_global_load_lds((const __attribute__((address_space(1))) void*)src,
                                     (__attribute__((address_space(3))) void*)dst,
                                     16, 0, 0);
  }
}

// 16x16x32 operand fragment (gemm kernels)
__device__ __forceinline__ bf16x8 rdfrag(const char* lds, int row, int kt, int lane) {
  int c = ((kt << 2) + (lane >> 4)) ^ (row & 7);
  return *(const bf16x8*)(lds + row * 128 + (c << 4));
}

// 32x32x16 operand fragment: row 0..63, chunk = kslice*2 + (lane>>5)
__device__ __forceinline__ bf16x8 rdfrag32(const char* lds, int row, int chunk) {
  int c = chunk ^ (row & 7);
  return *(const bf16x8*)(lds + row * 128 + (c << 4));
}

// Load 16 fp32 in the 32x32 C/D reg layout: reg r <- p[(r&3) + 8*(r>>2)]
// (caller passes p already offset by +4*hi and tile base)
__device__ __forceinline__ f32x16 loadb16(const float* p) {
  f32x16 r;
#pragma unroll
  for (int qd = 0; qd < 4; ++qd) {
    float4 v = *(const float4*)(p + qd * 8);
    r[qd * 4 + 0] = v.x; r[qd * 4 + 1] = v.y; r[qd * 4 + 2] = v.z; r[qd * 4 + 3] = v.w;
  }
  return r;
}

// Build a 32x32x16 A/B-frag (8 bf16, k = hi*8 + e) from 16 C/D-layout f32 regs
// (r0..r3 -> offsets 0..3(+4hi), r4..r7 -> 8..11(+4hi)) via cvt_pk + permlane32_swap.
__device__ __forceinline__ bf16x8 pk_swap(float r0, float r1, float r2, float r3,
                                          float r4, float r5, float r6, float r7) {
  unsigned a, b, c, d;
  asm("v_cvt_pk_bf16_f32 %0, %1, %2" : "=v"(a) : "v"(r0), "v"(r1));
  asm("v_cvt_pk_bf16_f32 %0, %1, %2" : "=v"(b) : "v"(r4), "v"(r5));
  asm("v_cvt_pk_bf16_f32 %0, %1, %2" : "=v"(c) : "v"(r2), "v"(r3));
  asm("v_cvt_pk_bf16_f32 %0, %1, %2" : "=v"(d) : "v"(r6), "v"(r7));
  asm("v_permlane32_swap_b32 %0, %1" : "+v"(a), "+v"(b));
  asm("v_permlane32_swap_b32 %0, %1" : "+v"(c), "+v"(d));
  union { unsigned u[4]; bf16x8 v; } r;
  r.u[0] = a; r.u[1] = c; r.u[2] = b; r.u[3] = d;
  return r.v;
}

// ---------------- GEMM: C = A @ B^T, A[M][K] bf16, B[N][K] bf16 ----------------
template<int MODE>
__global__ __launch_bounds__(256) void gemm_bt(const unsigned short* __restrict__ A,
                                               const unsigned short* __restrict__ B,
                                               void* __restrict__ C, int K) {
  __shared__ __attribute__((aligned(16))) char As[8192];
  __shared__ __attribute__((aligned(16))) char Bs[8192];
  int tid = threadIdx.x, w = tid >> 6, lane = tid & 63;
  int bm = blockIdx.x, bn = blockIdx.y;
  const char* Ab = (const char*)A + (size_t)bm * 64 * (K * 2);
  const char* Bb = (const char*)B + (size_t)bn * 64 * (K * 2);
  f32x4 acc[4] = {};
  int nsteps = K >> 6;
  for (int kk = 0; kk < nsteps; ++kk) {
    __syncthreads();
    stage64(Ab + (size_t)kk * 128, (size_t)K * 2, As, w, lane);
    stage64(Bb + (size_t)kk * 128, (size_t)K * 2, Bs, w, lane);
    __syncthreads();
#pragma unroll
    for (int kt = 0; kt < 2; ++kt) {
      bf16x8 a = rdfrag(As, w * 16 + (lane & 15), kt, lane);
#pragma unroll
      for (int nj = 0; nj < 4; ++nj) {
        bf16x8 b = rdfrag(Bs, nj * 16 + (lane & 15), kt, lane);
        acc[nj] = __builtin_amdgcn_mfma_f32_16x16x32_bf16(a, b, acc[nj], 0, 0, 0);
      }
    }
  }
  int g = lane >> 4, fr = lane & 15;
  if (MODE == 0) {
    unsigned short* vt = (unsigned short*)C;
    int growbase = bm * 64 + w * 16 + g * 4;
    int b = growbase >> 11;
    int n = growbase & 2047;
#pragma unroll
    for (int nj = 0; nj < 4; ++nj) {
      int d = nj * 16 + fr;
      unsigned short p0 = f2bf(acc[nj][0]), p1 = f2bf(acc[nj][1]);
      unsigned short p2 = f2bf(acc[nj][2]), p3 = f2bf(acc[nj][3]);
      uint2 u;
      u.x = (unsigned)p0 | ((unsigned)p1 << 16);
      u.y = (unsigned)p2 | ((unsigned)p3 << 16);
      *(uint2*)(vt + ((size_t)((b * 16 + bn) * 64 + d)) * 2048 + n) = u;
    }
  } else {
    float* Cf = (float*)C;
    int grow = bm * 64 + w * 16 + g * 4;
#pragma unroll
    for (int nj = 0; nj < 4; ++nj) {
#pragma unroll
      for (int r = 0; r < 4; ++r) {
        Cf[(size_t)(grow + r) * 1024 + bn * 64 + nj * 16 + fr] = acc[nj][r];
      }
    }
  }
}

// ---------------- fused dense attention (32x32 MFMA) ----------------
// Block: 128 q rows, 4 waves (wave owns q = w*32 + lane&31). m-step 64.
// Swapped QK^T: S^T = mfma32(K, Q) -> D[row=m][col=q]; bias C-init (log2 domain).
// P -> PV A-frags fully in-register (cvt_pk + permlane32_swap). o = mfma32(P, V).
__global__ __launch_bounds__(256) void flash_kernel(const unsigned short* __restrict__ xb,
                                                    const unsigned short* __restrict__ w1b,
                                                    const float* __restrict__ b1,
                                                    const unsigned short* __restrict__ w2b,
                                                    const float* __restrict__ b2l,
                                                    const unsigned short* __restrict__ vt,
                                                    unsigned short* __restrict__ aout) {
  __shared__ __attribute__((aligned(16))) char Kbuf[16384];   // K dbuf / prologue x-tile
  __shared__ __attribute__((aligned(16))) char Vbuf[16384];   // V dbuf / prologue W1
  int tid = threadIdx.x, w = tid >> 6, lane = tid & 63;
  int l31 = lane & 31, hi = lane >> 5;
  // XCD-chunked swizzle: 512 blocks, 8 XCDs -> same-bh blocks co-XCD
  int f = blockIdx.x;
  int swz = ((f & 7) << 6) | (f >> 3);
  int qt = swz & 15, bh = swz >> 4;
  int b = bh >> 4, h = bh & 15;

  // ---- prologue: Q = relu(xh @ W1^T + b1) * log2e, in-register ----
  const char* px = (const char*)(xb + ((size_t)(b * 2048 + qt * 128)) * 1024 + h * 64);
  stage64(px, 2048, Kbuf, w, lane);                 // x rows 0..63
  stage64(px + (size_t)64 * 2048, 2048, Kbuf + 8192, w, lane);  // x rows 64..127
  stage64((const char*)w1b, 128, Vbuf, w, lane);    // W1 rows e 0..63
  __syncthreads();

  f32x16 h0 = loadb16(b1 + hi * 4);                 // b1 as C-init (etile 0)
  f32x16 h1 = loadb16(b1 + 32 + hi * 4);            // etile 1
#pragma unroll
  for (int ks = 0; ks < 4; ++ks) {
    bf16x8 xf = rdfrag32(Kbuf, w * 32 + l31, ks * 2 + hi);    // B: x^T (col=q)
    bf16x8 wf0 = rdfrag32(Vbuf, l31, ks * 2 + hi);            // A: W1 rows e
    h0 = __builtin_amdgcn_mfma_f32_32x32x16_bf16(wf0, xf, h0, 0, 0, 0);
    bf16x8 wf1 = rdfrag32(Vbuf, 32 + l31, ks * 2 + hi);
    h1 = __builtin_amdgcn_mfma_f32_32x32x16_bf16(wf1, xf, h1, 0, 0, 0);
  }
#pragma unroll
  for (int i = 0; i < 16; ++i) {
    h0[i] = fmaxf(h0[i], 0.f) * LOG2E;
    h1[i] = fmaxf(h1[i], 0.f) * LOG2E;
  }
  bf16x8 qb[4];
  qb[0] = pk_swap(h0[0], h0[1], h0[2], h0[3], h0[4], h0[5], h0[6], h0[7]);
  qb[1] = pk_swap(h0[8], h0[9], h0[10], h0[11], h0[12], h0[13], h0[14], h0[15]);
  qb[2] = pk_swap(h1[0], h1[1], h1[2], h1[3], h1[4], h1[5], h1[6], h1[7]);
  qb[3] = pk_swap(h1[8], h1[9], h1[10], h1[11], h1[12], h1[13], h1[14], h1[15]);
  __syncthreads();                                  // all waves done with prologue LDS

  // ---- stage m-tile 0 + initial bias prefetch ----
  const char* vtb = (const char*)vt + (size_t)bh * 64 * 4096;
  stage64((const char*)w2b, 128, Kbuf, w, lane);
  stage64(vtb, 4096, Vbuf, w, lane);
  float4 pre[8];
#pragma unroll
  for (int pq = 0; pq < 4; ++pq) {
    pre[pq]     = *(const float4*)(b2l + pq * 8 + hi * 4);
    pre[pq + 4] = *(const float4*)(b2l + 32 + pq * 8 + hi * 4);
  }
  f32x16 oA = {}, oB = {};
  float lrs0 = 0.f, lrs1 = 0.f, lrs2 = 0.f, lrs3 = 0.f;
  __syncthreads();                                  // tile 0 landed

  for (int mt = 0; mt < 32; ++mt) {
    int cur = mt & 1;
    const char* Kc = Kbuf + (cur << 13);
    const char* Vc = Vbuf + (cur << 13);
    if (mt < 31) {                                  // stage next tile first
      stage64((const char*)w2b + (size_t)(mt + 1) * 8192, 128, Kbuf + ((cur ^ 1) << 13), w, lane);
      stage64(vtb + (size_t)(mt + 1) * 128, 4096, Vbuf + ((cur ^ 1) << 13), w, lane);
    }
    // S^T = K @ Q + bias (log2 domain), C-init from prefetched bias
    f32x16 s0, s1;
#pragma unroll
    for (int qd = 0; qd < 4; ++qd) {
      s0[qd * 4 + 0] = pre[qd].x;     s0[qd * 4 + 1] = pre[qd].y;
      s0[qd * 4 + 2] = pre[qd].z;     s0[qd * 4 + 3] = pre[qd].w;
      s1[qd * 4 + 0] = pre[qd + 4].x; s1[qd * 4 + 1] = pre[qd + 4].y;
      s1[qd * 4 + 2] = pre[qd + 4].z; s1[qd * 4 + 3] = pre[qd + 4].w;
    }
#pragma unroll
    for (int kt = 0; kt < 4; ++kt) {
      bf16x8 kf0 = rdfrag32(Kc, l31, kt * 2 + hi);
      s0 = __builtin_amdgcn_mfma_f32_32x32x16_bf16(kf0, qb[kt], s0, 0, 0, 0);
      bf16x8 kf1 = rdfrag32(Kc, 32 + l31, kt * 2 + hi);
      s1 = __builtin_amdgcn_mfma_f32_32x32x16_bf16(kf1, qb[kt], s1, 0, 0, 0);
    }
    if (mt < 31) {                                  // prefetch next bias
#pragma unroll
      for (int pq = 0; pq < 4; ++pq) {
        pre[pq]     = *(const float4*)(b2l + (mt + 1) * 64 + pq * 8 + hi * 4);
        pre[pq + 4] = *(const float4*)(b2l + (mt + 1) * 64 + 32 + pq * 8 + hi * 4);
      }
    }
    // p = 2^s ; 4-way split row-sum accumulate
#pragma unroll
    for (int i = 0; i < 16; ++i) {
      float t0, t1;
      asm("v_exp_f32 %0, %1" : "=v"(t0) : "v"(s0[i]));
      asm("v_exp_f32 %0, %1" : "=v"(t1) : "v"(s1[i]));
      s0[i] = t0; s1[i] = t1;
      if ((i & 3) == 0) { lrs0 += t0; lrs0 += t1; }
      else if ((i & 3) == 1) { lrs1 += t0; lrs1 += t1; }
      else if ((i & 3) == 2) { lrs2 += t0; lrs2 += t1; }
      else { lrs3 += t0; lrs3 += t1; }
    }
    // P -> A-frags in-register
    bf16x8 pa[4];
    pa[0] = pk_swap(s0[0], s0[1], s0[2], s0[3], s0[4], s0[5], s0[6], s0[7]);
    pa[1] = pk_swap(s0[8], s0[9], s0[10], s0[11], s0[12], s0[13], s0[14], s0[15]);
    pa[2] = pk_swap(s1[0], s1[1], s1[2], s1[3], s1[4], s1[5], s1[6], s1[7]);
    pa[3] = pk_swap(s1[8], s1[9], s1[10], s1[11], s1[12], s1[13], s1[14], s1[15]);
    // O += P @ V
#pragma unroll
    for (int ks = 0; ks < 4; ++ks) {
      bf16x8 vf0 = rdfrag32(Vc, l31, ks * 2 + hi);
      oA = __builtin_amdgcn_mfma_f32_32x32x16_bf16(pa[ks], vf0, oA, 0, 0, 0);
      bf16x8 vf1 = rdfrag32(Vc, 32 + l31, ks * 2 + hi);
      oB = __builtin_amdgcn_mfma_f32_32x32x16_bf16(pa[ks], vf1, oB, 0, 0, 0);
    }
    __syncthreads();                                // next tile landed; cur consumed
  }

  // ---- finalize ----
  float l = (lrs0 + lrs1) + (lrs2 + lrs3);          // partial sum for q=l31 (own half)
  l += __shfl_xor(l, 32);                           // + partner half -> full row sum
  float inv = 1.f / l;
  float iv[16];
#pragma unroll
  for (int r = 0; r < 16; ++r)
    iv[r] = __shfl(inv, (r & 3) + 8 * (r >> 2) + 4 * hi);
  int nb = qt * 128 + w * 32;
#pragma unroll
  for (int r = 0; r < 16; ++r) {
    int ql = (r & 3) + 8 * (r >> 2) + 4 * hi;
    size_t off = ((size_t)(b * 2048 + nb + ql)) * 1024 + h * 64 + l31;
    aout[off]      = f2bf(oA[r] * iv[r]);
    aout[off + 32] = f2bf(oB[r] * iv[r]);
  }
}

// ---------------- launch ----------------
extern "C" void kernel_launch(void* const* d_in, const int* in_sizes, int n_in,
                              void* d_out, int out_size, void* d_ws, size_t ws_size,
                              hipStream_t stream) {
  (void)in_sizes; (void)n_in; (void)out_size; (void)ws_size;
  const float* x  = (const float*)d_in[0];
  const float* W1 = (const float*)d_in[1];
  const float* b1 = (const float*)d_in[2];
  const float* W2 = (const float*)d_in[3];
  const float* b2 = (const float*)d_in[4];
  const float* Wv = (const float*)d_in[5];
  const float* Wo = (const float*)d_in[6];
  float* out = (float*)d_out;

  char* ws = (char*)d_ws;
  unsigned short* xb   = (unsigned short*)(ws);             // x bf16      8 MB
  unsigned short* wvb  = (unsigned short*)(ws +  8388608);  // Wv bf16     2 MB
  unsigned short* wob  = (unsigned short*)(ws + 10485760);  // Wo bf16     2 MB
  unsigned short* w2b  = (unsigned short*)(ws + 12582912);  // W2 bf16   256 KB
  unsigned short* w1b  = (unsigned short*)(ws + 12845056);  // W1 bf16     8 KB
  float*          b2l  = (float*)         (ws + 12853248);  // b2*log2e    8 KB
  unsigned short* vt   = (unsigned short*)(ws + 21233664);  // V^T bf16    8 MB
  unsigned short* aout = (unsigned short*)(ws + 29622272);  // out_h bf16  8 MB

  conv_bf16<<<1024, 256, 0, stream>>>(x,  xb,  4194304 / 4);
  conv_bf16<<<1024, 256, 0, stream>>>(Wv, wvb, 1048576 / 4);
  conv_bf16<<<1024, 256, 0, stream>>>(Wo, wob, 1048576 / 4);
  conv_bf16<<< 128, 256, 0, stream>>>(W2, w2b,  131072 / 4);
  conv_bf16<<<   4, 256, 0, stream>>>(W1, w1b,    4096 / 4);
  b2l_kernel<<<   8, 256, 0, stream>>>(b2, b2l, 2048);

  // value = x @ Wv^T -> vt[bh][d][m]
  gemm_bt<0><<<dim3(64, 16), 256, 0, stream>>>(xb, wvb, (void*)vt, 1024);
  // fused: Q = relu(xh@W1^T+b1); softmax(Q@W2^T + b2) @ V -> aout (merged heads)
  flash_kernel<<<512, 256, 0, stream>>>(xb, w1b, b1, w2b, b2l, vt, aout);
  // out = aout @ Wo^T (fp32)
  gemm_bt<1><<<dim3(64, 16), 256, 0, stream>>>(aout, wob, (void*)out, 1024);
}

// Round 7
// 101.502 us; speedup vs baseline: 2.6563x; 1.0907x over previous
//
#include <hip/hip_runtime.h>
#include <hip/hip_bf16.h>
#include <math.h>
#include <stdint.h>

// MultiHeadDenseAttention: B=2, H=16, N=2048, D=64, F=1024, M=2048
//  value = x @ Wv^T (*exp(b2) col-scale) -> vt[bh][d][m]   (128x128 GEMM)
//  hid   = relu(xh @ W1^T + b1)      (fused into flash prologue, MFMA 32x32)
//  attn  = softmax(hid @ W2^T + b2)  (flash, swapped-QK^T, exp2, no-max,
//                                     bias folded into V-scale + L-MFMA denom)
//  out_h = attn @ vh                 (fused, P in-register via cvt_pk+permlane)
//  out   = merge(out_h) @ Wo^T       (128x128 GEMM, fp32 out)

typedef __attribute__((ext_vector_type(8))) short bf16x8;
typedef __attribute__((ext_vector_type(4))) float f32x4;
typedef __attribute__((ext_vector_type(16))) float f32x16;

#define LOG2E 1.4426950408889634f

__device__ __forceinline__ unsigned short f2bf(float f) {
  union { float f; unsigned u; } v; v.f = f;
  unsigned r = v.u + 0x7FFFu + ((v.u >> 16) & 1u);   // round-to-nearest-even
  return (unsigned short)(r >> 16);
}

// ---------------- fp32 -> bf16 convert (x) ----------------
__global__ __launch_bounds__(256) void conv_bf16(const float* __restrict__ src,
                                                 unsigned short* __restrict__ dst, int nq) {
  int stride = gridDim.x * blockDim.x;
  for (int q = blockIdx.x * blockDim.x + threadIdx.x; q < nq; q += stride) {
    float4 v = *(const float4*)(src + (size_t)q * 4);
    uint2 u;
    u.x = (unsigned)f2bf(v.x) | ((unsigned)f2bf(v.y) << 16);
    u.y = (unsigned)f2bf(v.z) | ((unsigned)f2bf(v.w) << 16);
    *(uint2*)(dst + (size_t)q * 4) = u;
  }
}

// ---------------- one-shot prep: Wv/Wo/W2/W1 -> bf16, b2 -> exp tables ---------
__global__ __launch_bounds__(256) void prep_kernel(const float* __restrict__ Wv,
                                                   const float* __restrict__ Wo,
                                                   const float* __restrict__ W2,
                                                   const float* __restrict__ W1,
                                                   const float* __restrict__ b2,
                                                   unsigned short* __restrict__ wvb,
                                                   unsigned short* __restrict__ wob,
                                                   unsigned short* __restrict__ w2b,
                                                   unsigned short* __restrict__ w1b,
                                                   float* __restrict__ eb2f,
                                                   unsigned short* __restrict__ ebb) {
  int bid = blockIdx.x;
  if (bid == 1024) {                                 // exp(b2) tables
    int i = threadIdx.x;
#pragma unroll
    for (int t = 0; t < 8; ++t) {
      int k = i * 8 + t;
      float e = __expf(b2[k]);
      eb2f[k] = e;
      ebb[k] = f2bf(e);
    }
    return;
  }
  int stride = 1024 * 256;
  for (int q = bid * 256 + threadIdx.x; q < 558080; q += stride) {
    const float* s; unsigned short* d; int o;
    if (q < 262144)      { s = Wv; d = wvb; o = q; }
    else if (q < 524288) { s = Wo; d = wob; o = q - 262144; }
    else if (q < 557056) { s = W2; d = w2b; o = q - 524288; }
    else                 { s = W1; d = w1b; o = q - 557056; }
    float4 v = *(const float4*)(s + (size_t)o * 4);
    uint2 u;
    u.x = (unsigned)f2bf(v.x) | ((unsigned)f2bf(v.y) << 16);
    u.y = (unsigned)f2bf(v.z) | ((unsigned)f2bf(v.w) << 16);
    *(uint2*)(d + (size_t)o * 4) = u;
  }
}

// ---------------- shared staging/frag helpers ----------------
// Stage a 64-row x 128-byte tile into 8KB of LDS via global_load_lds.
// LDS(row, chunk c') holds global chunk c' ^ (row&7)  (XOR swizzle via source addr).
__device__ __forceinline__ void stage64(const char* g, size_t ldbytes, char* lds,
                                        int w, int lane) {
#pragma unroll
  for (int t = 0; t < 2; ++t) {
    int row  = w * 16 + t * 8 + (lane >> 3);      // row & 7 == lane>>3
    int csrc = (lane & 7) ^ (lane >> 3);          // inverse-swizzled source chunk
    const char* src = g + (size_t)row * ldbytes + (csrc << 4);
    char* dst = lds + ((w * 2 + t) << 10);        // wave-uniform base; HW adds lane*16
    __builtin_amdgcn_global_load_lds((const __attribute__((address_space(1))) void*)src,
                                     (__attribute__((address_space(3))) void*)dst,
                                     16, 0, 0);
  }
}

// 32x32x16 operand fragment: row 0..63, chunk = kslice*2 + (lane>>5)
__device__ __forceinline__ bf16x8 rdfrag32(const char* lds, int row, int chunk) {
  int c = chunk ^ (row & 7);
  return *(const bf16x8*)(lds + row * 128 + (c << 4));
}

// Load 16 fp32 in the 32x32 C/D reg layout: reg r <- p[(r&3) + 8*(r>>2)]
__device__ __forceinline__ f32x16 loadb16(const float* p) {
  f32x16 r;
#pragma unroll
  for (int qd = 0; qd < 4; ++qd) {
    float4 v = *(const float4*)(p + qd * 8);
    r[qd * 4 + 0] = v.x; r[qd * 4 + 1] = v.y; r[qd * 4 + 2] = v.z; r[qd * 4 + 3] = v.w;
  }
  return r;
}

// Build a 32x32x16 A/B-frag (8 bf16) from 16 C/D-layout f32 regs via cvt_pk+permlane.
__device__ __forceinline__ bf16x8 pk_swap(float r0, float r1, float r2, float r3,
                                          float r4, float r5, float r6, float r7) {
  unsigned a, b, c, d;
  asm("v_cvt_pk_bf16_f32 %0, %1, %2" : "=v"(a) : "v"(r0), "v"(r1));
  asm("v_cvt_pk_bf16_f32 %0, %1, %2" : "=v"(b) : "v"(r4), "v"(r5));
  asm("v_cvt_pk_bf16_f32 %0, %1, %2" : "=v"(c) : "v"(r2), "v"(r3));
  asm("v_cvt_pk_bf16_f32 %0, %1, %2" : "=v"(d) : "v"(r6), "v"(r7));
  asm("v_permlane32_swap_b32 %0, %1" : "+v"(a), "+v"(b));
  asm("v_permlane32_swap_b32 %0, %1" : "+v"(c), "+v"(d));
  union { unsigned u[4]; bf16x8 v; } r;
  r.u[0] = a; r.u[1] = c; r.u[2] = b; r.u[3] = d;
  return r.v;
}

// ---------------- GEMM: C = A @ B^T, 128x128 tile, 32x32 MFMA ----------------
// 4 waves in 2x2; wave computes 64x64 (2x2 of 32x32). Double-buffered staging.
// MODE 0: vt[bh*64+d][2048] bf16, columns (rows of A) scaled by eb2f[m & 2047]
// MODE 1: fp32 row-major [M][1024]
template<int MODE>
__global__ __launch_bounds__(256) void gemm128(const unsigned short* __restrict__ A,
                                               const unsigned short* __restrict__ B,
                                               void* __restrict__ C,
                                               const float* __restrict__ eb2f, int K) {
  __shared__ __attribute__((aligned(16))) char As[2][16384];
  __shared__ __attribute__((aligned(16))) char Bs[2][16384];
  int tid = threadIdx.x, w = tid >> 6, lane = tid & 63;
  int l31 = lane & 31, hi = lane >> 5;
  int wr = w >> 1, wc = w & 1;
  int bm = blockIdx.x, bn = blockIdx.y;
  const char* Ab = (const char*)A + (size_t)bm * 128 * (K * 2);
  const char* Bb = (const char*)B + (size_t)bn * 128 * (K * 2);
  size_t ld = (size_t)K * 2;

  f32x16 acc00 = {}, acc01 = {}, acc10 = {}, acc11 = {};
  // stage tile 0
  stage64(Ab, ld, As[0], w, lane);
  stage64(Ab + 64 * ld, ld, As[0] + 8192, w, lane);
  stage64(Bb, ld, Bs[0], w, lane);
  stage64(Bb + 64 * ld, ld, Bs[0] + 8192, w, lane);
  __syncthreads();

  int nst = K >> 6;
  for (int kk = 0; kk < nst; ++kk) {
    int cur = kk & 1;
    if (kk + 1 < nst) {
      const char* An = Ab + (size_t)(kk + 1) * 128;
      const char* Bn = Bb + (size_t)(kk + 1) * 128;
      stage64(An, ld, As[cur ^ 1], w, lane);
      stage64(An + 64 * ld, ld, As[cur ^ 1] + 8192, w, lane);
      stage64(Bn, ld, Bs[cur ^ 1], w, lane);
      stage64(Bn + 64 * ld, ld, Bs[cur ^ 1] + 8192, w, lane);
    }
    __builtin_amdgcn_s_setprio(1);
#pragma unroll
    for (int ks = 0; ks < 4; ++ks) {
      bf16x8 a0 = rdfrag32(As[cur], wr * 64 + l31, ks * 2 + hi);
      bf16x8 a1 = rdfrag32(As[cur], wr * 64 + 32 + l31, ks * 2 + hi);
      bf16x8 b0 = rdfrag32(Bs[cur], wc * 64 + l31, ks * 2 + hi);
      bf16x8 b1 = rdfrag32(Bs[cur], wc * 64 + 32 + l31, ks * 2 + hi);
      acc00 = __builtin_amdgcn_mfma_f32_32x32x16_bf16(a0, b0, acc00, 0, 0, 0);
      acc01 = __builtin_amdgcn_mfma_f32_32x32x16_bf16(a0, b1, acc01, 0, 0, 0);
      acc10 = __builtin_amdgcn_mfma_f32_32x32x16_bf16(a1, b0, acc10, 0, 0, 0);
      acc11 = __builtin_amdgcn_mfma_f32_32x32x16_bf16(a1, b1, acc11, 0, 0, 0);
    }
    __builtin_amdgcn_s_setprio(0);
    __syncthreads();
  }

  if (MODE == 0) {
    unsigned short* vt = (unsigned short*)C;
#pragma unroll
    for (int i = 0; i < 2; ++i) {
      int rowb = bm * 128 + wr * 64 + i * 32;
#pragma unroll
      for (int qd = 0; qd < 4; ++qd) {
        int m0 = rowb + qd * 8 + hi * 4;          // 4 consecutive m (r=qd*4+0..3)
        float4 e4 = *(const float4*)(eb2f + (m0 & 2047));   // seq pos = m0 mod 2048
        int bb = m0 >> 11, n = m0 & 2047;
#pragma unroll
        for (int j = 0; j < 2; ++j) {
          int h = bn * 2 + wc, d = j * 32 + l31;
          f32x16 a = (i == 0) ? (j == 0 ? acc00 : acc01) : (j == 0 ? acc10 : acc11);
          int r0 = qd * 4;
          uint2 u;
          u.x = (unsigned)f2bf(a[r0] * e4.x) | ((unsigned)f2bf(a[r0 + 1] * e4.y) << 16);
          u.y = (unsigned)f2bf(a[r0 + 2] * e4.z) | ((unsigned)f2bf(a[r0 + 3] * e4.w) << 16);
          *(uint2*)(vt + ((size_t)((bb * 16 + h) * 64 + d)) * 2048 + n) = u;
        }
      }
    }
  } else {
    float* Cf = (float*)C;
    int rb = bm * 128 + wr * 64, cb = bn * 128 + wc * 64;
#pragma unroll
    for (int r = 0; r < 16; ++r) {
      int row = (r & 3) + 8 * (r >> 2) + 4 * hi;
      Cf[(size_t)(rb + row) * 1024 + cb + l31]          = acc00[r];
      Cf[(size_t)(rb + row) * 1024 + cb + 32 + l31]     = acc01[r];
      Cf[(size_t)(rb + 32 + row) * 1024 + cb + l31]     = acc10[r];
      Cf[(size_t)(rb + 32 + row) * 1024 + cb + 32 + l31] = acc11[r];
    }
  }
}

// ---------------- fused dense attention (32x32 MFMA) ----------------
// Block: 128 q rows, 4 waves (wave owns q = w*32 + lane&31). m-step 64.
// Swapped QK^T: S^T = mfma32(K, Q); p = 2^s (Q pre-scaled by log2e; bias folded
// into V-scale). Denominator L via MFMA vs exp(b2) bf16 frags (same D-layout as O).
__global__ __launch_bounds__(256) void flash_kernel(const unsigned short* __restrict__ xb,
                                                    const unsigned short* __restrict__ w1b,
                                                    const float* __restrict__ b1,
                                                    const unsigned short* __restrict__ w2b,
                                                    const unsigned short* __restrict__ ebb,
                                                    const unsigned short* __restrict__ vt,
                                                    unsigned short* __restrict__ aout) {
  __shared__ __attribute__((aligned(16))) char Kbuf[16384];   // K dbuf / prologue x-tile
  __shared__ __attribute__((aligned(16))) char Vbuf[16384];   // V dbuf / prologue W1
  int tid = threadIdx.x, w = tid >> 6, lane = tid & 63;
  int l31 = lane & 31, hi = lane >> 5;
  // XCD-chunked swizzle: 512 blocks, 8 XCDs -> same-bh blocks co-XCD
  int f = blockIdx.x;
  int swz = ((f & 7) << 6) | (f >> 3);
  int qt = swz & 15, bh = swz >> 4;
  int b = bh >> 4, h = bh & 15;

  // ---- prologue: Q = relu(xh @ W1^T + b1) * log2e, in-register ----
  const char* px = (const char*)(xb + ((size_t)(b * 2048 + qt * 128)) * 1024 + h * 64);
  stage64(px, 2048, Kbuf, w, lane);                 // x rows 0..63
  stage64(px + (size_t)64 * 2048, 2048, Kbuf + 8192, w, lane);  // x rows 64..127
  stage64((const char*)w1b, 128, Vbuf, w, lane);    // W1 rows e 0..63
  __syncthreads();

  f32x16 h0 = loadb16(b1 + hi * 4);                 // b1 as C-init (etile 0)
  f32x16 h1 = loadb16(b1 + 32 + hi * 4);            // etile 1
#pragma unroll
  for (int ks = 0; ks < 4; ++ks) {
    bf16x8 xf = rdfrag32(Kbuf, w * 32 + l31, ks * 2 + hi);    // B: x^T (col=q)
    bf16x8 wf0 = rdfrag32(Vbuf, l31, ks * 2 + hi);            // A: W1 rows e
    h0 = __builtin_amdgcn_mfma_f32_32x32x16_bf16(wf0, xf, h0, 0, 0, 0);
    bf16x8 wf1 = rdfrag32(Vbuf, 32 + l31, ks * 2 + hi);
    h1 = __builtin_amdgcn_mfma_f32_32x32x16_bf16(wf1, xf, h1, 0, 0, 0);
  }
#pragma unroll
  for (int i = 0; i < 16; ++i) {
    h0[i] = fmaxf(h0[i], 0.f) * LOG2E;
    h1[i] = fmaxf(h1[i], 0.f) * LOG2E;
  }
  bf16x8 qb[4];
  qb[0] = pk_swap(h0[0], h0[1], h0[2], h0[3], h0[4], h0[5], h0[6], h0[7]);
  qb[1] = pk_swap(h0[8], h0[9], h0[10], h0[11], h0[12], h0[13], h0[14], h0[15]);
  qb[2] = pk_swap(h1[0], h1[1], h1[2], h1[3], h1[4], h1[5], h1[6], h1[7]);
  qb[3] = pk_swap(h1[8], h1[9], h1[10], h1[11], h1[12], h1[13], h1[14], h1[15]);
  __syncthreads();                                  // all waves done with prologue LDS

  // ---- stage m-tile 0 ----
  const char* vtb = (const char*)vt + (size_t)bh * 64 * 4096;
  stage64((const char*)w2b, 128, Kbuf, w, lane);
  stage64(vtb, 4096, Vbuf, w, lane);

  const f32x16 zro = {};
  f32x16 oA = {}, oB = {}, L = {};
  __syncthreads();                                  // tile 0 landed

  for (int mt = 0; mt < 32; ++mt) {
    int cur = mt & 1;
    const char* Kc = Kbuf + (cur << 13);
    const char* Vc = Vbuf + (cur << 13);
    if (mt < 31) {                                  // stage next tile first
      stage64((const char*)w2b + (size_t)(mt + 1) * 8192, 128, Kbuf + ((cur ^ 1) << 13), w, lane);
      stage64(vtb + (size_t)(mt + 1) * 128, 4096, Vbuf + ((cur ^ 1) << 13), w, lane);
    }
    // exp(b2) fragments for denominator (k-order matches V-frags)
    bf16x8 ebf0 = *(const bf16x8*)(ebb + mt * 64 + hi * 8);
    bf16x8 ebf1 = *(const bf16x8*)(ebb + mt * 64 + 16 + hi * 8);
    bf16x8 ebf2 = *(const bf16x8*)(ebb + mt * 64 + 32 + hi * 8);
    bf16x8 ebf3 = *(const bf16x8*)(ebb + mt * 64 + 48 + hi * 8);

    // S^T = K @ Q (log2 domain)
    f32x16 s0 = zro, s1 = zro;
    __builtin_amdgcn_s_setprio(1);
#pragma unroll
    for (int kt = 0; kt < 4; ++kt) {
      bf16x8 kf0 = rdfrag32(Kc, l31, kt * 2 + hi);
      s0 = __builtin_amdgcn_mfma_f32_32x32x16_bf16(kf0, qb[kt], s0, 0, 0, 0);
      bf16x8 kf1 = rdfrag32(Kc, 32 + l31, kt * 2 + hi);
      s1 = __builtin_amdgcn_mfma_f32_32x32x16_bf16(kf1, qb[kt], s1, 0, 0, 0);
    }
    __builtin_amdgcn_s_setprio(0);
    // p = 2^s
#pragma unroll
    for (int i = 0; i < 16; ++i) {
      float t0, t1;
      asm("v_exp_f32 %0, %1" : "=v"(t0) : "v"(s0[i]));
      asm("v_exp_f32 %0, %1" : "=v"(t1) : "v"(s1[i]));
      s0[i] = t0; s1[i] = t1;
    }
    // P -> A-frags in-register
    bf16x8 pa0 = pk_swap(s0[0], s0[1], s0[2], s0[3], s0[4], s0[5], s0[6], s0[7]);
    bf16x8 pa1 = pk_swap(s0[8], s0[9], s0[10], s0[11], s0[12], s0[13], s0[14], s0[15]);
    bf16x8 pa2 = pk_swap(s1[0], s1[1], s1[2], s1[3], s1[4], s1[5], s1[6], s1[7]);
    bf16x8 pa3 = pk_swap(s1[8], s1[9], s1[10], s1[11], s1[12], s1[13], s1[14], s1[15]);
    // O += P @ V ; L += P @ exp(b2)
    __builtin_amdgcn_s_setprio(1);
    L = __builtin_amdgcn_mfma_f32_32x32x16_bf16(pa0, ebf0, L, 0, 0, 0);
    L = __builtin_amdgcn_mfma_f32_32x32x16_bf16(pa1, ebf1, L, 0, 0, 0);
    L = __builtin_amdgcn_mfma_f32_32x32x16_bf16(pa2, ebf2, L, 0, 0, 0);
    L = __builtin_amdgcn_mfma_f32_32x32x16_bf16(pa3, ebf3, L, 0, 0, 0);
    {
      bf16x8 vf;
      vf = rdfrag32(Vc, l31, 0 + hi);
      oA = __builtin_amdgcn_mfma_f32_32x32x16_bf16(pa0, vf, oA, 0, 0, 0);
      vf = rdfrag32(Vc, 32 + l31, 0 + hi);
      oB = __builtin_amdgcn_mfma_f32_32x32x16_bf16(pa0, vf, oB, 0, 0, 0);
      vf = rdfrag32(Vc, l31, 2 + hi);
      oA = __builtin_amdgcn_mfma_f32_32x32x16_bf16(pa1, vf, oA, 0, 0, 0);
      vf = rdfrag32(Vc, 32 + l31, 2 + hi);
      oB = __builtin_amdgcn_mfma_f32_32x32x16_bf16(pa1, vf, oB, 0, 0, 0);
      vf = rdfrag32(Vc, l31, 4 + hi);
      oA = __builtin_amdgcn_mfma_f32_32x32x16_bf16(pa2, vf, oA, 0, 0, 0);
      vf = rdfrag32(Vc, 32 + l31, 4 + hi);
      oB = __builtin_amdgcn_mfma_f32_32x32x16_bf16(pa2, vf, oB, 0, 0, 0);
      vf = rdfrag32(Vc, l31, 6 + hi);
      oA = __builtin_amdgcn_mfma_f32_32x32x16_bf16(pa3, vf, oA, 0, 0, 0);
      vf = rdfrag32(Vc, 32 + l31, 6 + hi);
      oB = __builtin_amdgcn_mfma_f32_32x32x16_bf16(pa3, vf, oB, 0, 0, 0);
    }
    __builtin_amdgcn_s_setprio(0);
    __syncthreads();                                // next tile landed; cur consumed
  }

  // ---- finalize: L[r] = denominator for the same q-row as oA[r]/oB[r] ----
  int nb = qt * 128 + w * 32;
#pragma unroll
  for (int r = 0; r < 16; ++r) {
    float iv = 1.f / L[r];
    int ql = (r & 3) + 8 * (r >> 2) + 4 * hi;
    size_t off = ((size_t)(b * 2048 + nb + ql)) * 1024 + h * 64 + l31;
    aout[off]      = f2bf(oA[r] * iv);
    aout[off + 32] = f2bf(oB[r] * iv);
  }
}

// ---------------- launch ----------------
extern "C" void kernel_launch(void* const* d_in, const int* in_sizes, int n_in,
                              void* d_out, int out_size, void* d_ws, size_t ws_size,
                              hipStream_t stream) {
  (void)in_sizes; (void)n_in; (void)out_size; (void)ws_size;
  const float* x  = (const float*)d_in[0];
  const float* W1 = (const float*)d_in[1];
  const float* b1 = (const float*)d_in[2];
  const float* W2 = (const float*)d_in[3];
  const float* b2 = (const float*)d_in[4];
  const float* Wv = (const float*)d_in[5];
  const float* Wo = (const float*)d_in[6];
  float* out = (float*)d_out;

  char* ws = (char*)d_ws;
  unsigned short* xb   = (unsigned short*)(ws);             // x bf16      8 MB
  unsigned short* wvb  = (unsigned short*)(ws +  8388608);  // Wv bf16     2 MB
  unsigned short* wob  = (unsigned short*)(ws + 10485760);  // Wo bf16     2 MB
  unsigned short* w2b  = (unsigned short*)(ws + 12582912);  // W2 bf16   256 KB
  unsigned short* w1b  = (unsigned short*)(ws + 12845056);  // W1 bf16     8 KB
  float*          eb2f = (float*)         (ws + 12853248);  // exp(b2)     8 KB
  unsigned short* ebb  = (unsigned short*)(ws + 12861440);  // exp(b2)bf16 4 KB
  unsigned short* vt   = (unsigned short*)(ws + 21233664);  // V^T bf16    8 MB
  unsigned short* aout = (unsigned short*)(ws + 29622272);  // out_h bf16  8 MB

  conv_bf16<<<1024, 256, 0, stream>>>(x, xb, 4194304 / 4);
  prep_kernel<<<1025, 256, 0, stream>>>(Wv, Wo, W2, W1, b2,
                                        wvb, wob, w2b, w1b, eb2f, ebb);

  // value = x @ Wv^T (cols scaled by exp(b2)) -> vt[bh][d][m]
  gemm128<0><<<dim3(32, 8), 256, 0, stream>>>(xb, wvb, (void*)vt, eb2f, 1024);
  // fused: Q = relu(xh@W1^T+b1); softmax(Q@W2^T + b2) @ V -> aout (merged heads)
  flash_kernel<<<512, 256, 0, stream>>>(xb, w1b, b1, w2b, ebb, vt, aout);
  // out = aout @ Wo^T (fp32)
  gemm128<1><<<dim3(32, 8), 256, 0, stream>>>(aout, wob, (void*)out, eb2f, 1024);
}

// Round 8
// 98.113 us; speedup vs baseline: 2.7480x; 1.0345x over previous
//
#include <hip/hip_runtime.h>
#include <hip/hip_bf16.h>
#include <math.h>
#include <stdint.h>

// MultiHeadDenseAttention: B=2, H=16, N=2048, D=64, F=1024, M=2048
//  value = x @ Wv^T (*exp(b2) col-scale) -> vt[bh][d][m]   (128x128 GEMM)
//  hid   = relu(xh @ W1^T + b1)      (fused into flash prologue, MFMA 32x32)
//  attn  = softmax(hid @ W2^T + b2)  (flash, swapped-QK^T, exp2, no-max,
//                                     bias folded into V-scale + L-MFMA denom)
//  out_h = attn @ vh                 (fused, P in-register, 8-wave m-parallel)
//  out   = merge(out_h) @ Wo^T       (128x128 GEMM, fp32 out)

typedef __attribute__((ext_vector_type(8))) short bf16x8;
typedef __attribute__((ext_vector_type(4))) float f32x4;
typedef __attribute__((ext_vector_type(16))) float f32x16;

#define LOG2E 1.4426950408889634f

__device__ __forceinline__ unsigned short f2bf(float f) {
  union { float f; unsigned u; } v; v.f = f;
  unsigned r = v.u + 0x7FFFu + ((v.u >> 16) & 1u);   // round-to-nearest-even
  return (unsigned short)(r >> 16);
}

// ------------- one-shot prep: x/Wv/Wo/W2/W1 -> bf16, b2 -> exp tables ---------
__global__ __launch_bounds__(256) void prep_all(const float* __restrict__ x,
                                                const float* __restrict__ Wv,
                                                const float* __restrict__ Wo,
                                                const float* __restrict__ W2,
                                                const float* __restrict__ W1,
                                                const float* __restrict__ b2,
                                                unsigned short* __restrict__ xb,
                                                unsigned short* __restrict__ wvb,
                                                unsigned short* __restrict__ wob,
                                                unsigned short* __restrict__ w2b,
                                                unsigned short* __restrict__ w1b,
                                                float* __restrict__ eb2f,
                                                unsigned short* __restrict__ ebb) {
  int bid = blockIdx.x;
  if (bid == 2048) {                                 // exp(b2) tables
    int i = threadIdx.x;
#pragma unroll
    for (int t = 0; t < 8; ++t) {
      int k = i * 8 + t;
      float e = __expf(b2[k]);
      eb2f[k] = e;
      ebb[k] = f2bf(e);
    }
    return;
  }
  int stride = 2048 * 256;
  for (int q = bid * 256 + threadIdx.x; q < 1606656; q += stride) {
    const float* s; unsigned short* d; int o;
    if (q < 1048576)      { s = x;  d = xb;  o = q; }
    else {
      int q2 = q - 1048576;
      if (q2 < 262144)      { s = Wv; d = wvb; o = q2; }
      else if (q2 < 524288) { s = Wo; d = wob; o = q2 - 262144; }
      else if (q2 < 557056) { s = W2; d = w2b; o = q2 - 524288; }
      else                  { s = W1; d = w1b; o = q2 - 557056; }
    }
    float4 v = *(const float4*)(s + (size_t)o * 4);
    uint2 u;
    u.x = (unsigned)f2bf(v.x) | ((unsigned)f2bf(v.y) << 16);
    u.y = (unsigned)f2bf(v.z) | ((unsigned)f2bf(v.w) << 16);
    *(uint2*)(d + (size_t)o * 4) = u;
  }
}

// ---------------- shared staging/frag helpers ----------------
// 4-wave version: wave w stages rows w*16..w*16+15 (2 insts)
__device__ __forceinline__ void stage64(const char* g, size_t ldbytes, char* lds,
                                        int w, int lane) {
#pragma unroll
  for (int t = 0; t < 2; ++t) {
    int row  = w * 16 + t * 8 + (lane >> 3);
    int csrc = (lane & 7) ^ (lane >> 3);
    const char* src = g + (size_t)row * ldbytes + (csrc << 4);
    char* dst = lds + ((w * 2 + t) << 10);
    __builtin_amdgcn_global_load_lds((const __attribute__((address_space(1))) void*)src,
                                     (__attribute__((address_space(3))) void*)dst,
                                     16, 0, 0);
  }
}

// 8-wave version: wave w stages rows w*8..w*8+7 (1 inst)
__device__ __forceinline__ void stage8(const char* g, size_t ldbytes, char* lds_,
                                       int w, int lane) {
  int row  = w * 8 + (lane >> 3);                 // row & 7 == lane>>3
  int csrc = (lane & 7) ^ (lane >> 3);
  const char* src = g + (size_t)row * ldbytes + (csrc << 4);
  char* dst = lds_ + (w << 10);
  __builtin_amdgcn_global_load_lds((const __attribute__((address_space(1))) void*)src,
                                   (__attribute__((address_space(3))) void*)dst,
                                   16, 0, 0);
}

// 32x32x16 operand fragment: row 0..63, chunk = kslice*2 + (lane>>5)
__device__ __forceinline__ bf16x8 rdfrag32(const char* lds, int row, int chunk) {
  int c = chunk ^ (row & 7);
  return *(const bf16x8*)(lds + row * 128 + (c << 4));
}

// Load 16 fp32 in the 32x32 C/D reg layout: reg r <- p[(r&3) + 8*(r>>2)]
__device__ __forceinline__ f32x16 loadb16(const float* p) {
  f32x16 r;
#pragma unroll
  for (int qd = 0; qd < 4; ++qd) {
    float4 v = *(const float4*)(p + qd * 8);
    r[qd * 4 + 0] = v.x; r[qd * 4 + 1] = v.y; r[qd * 4 + 2] = v.z; r[qd * 4 + 3] = v.w;
  }
  return r;
}

// Build a 32x32x16 A/B-frag (8 bf16) from 16 C/D-layout f32 regs via cvt_pk+permlane.
__device__ __forceinline__ bf16x8 pk_swap(float r0, float r1, float r2, float r3,
                                          float r4, float r5, float r6, float r7) {
  unsigned a, b, c, d;
  asm("v_cvt_pk_bf16_f32 %0, %1, %2" : "=v"(a) : "v"(r0), "v"(r1));
  asm("v_cvt_pk_bf16_f32 %0, %1, %2" : "=v"(b) : "v"(r4), "v"(r5));
  asm("v_cvt_pk_bf16_f32 %0, %1, %2" : "=v"(c) : "v"(r2), "v"(r3));
  asm("v_cvt_pk_bf16_f32 %0, %1, %2" : "=v"(d) : "v"(r6), "v"(r7));
  asm("v_permlane32_swap_b32 %0, %1" : "+v"(a), "+v"(b));
  asm("v_permlane32_swap_b32 %0, %1" : "+v"(c), "+v"(d));
  union { unsigned u[4]; bf16x8 v; } r;
  r.u[0] = a; r.u[1] = c; r.u[2] = b; r.u[3] = d;
  return r.v;
}

// ---------------- GEMM: C = A @ B^T, 128x128 tile, 32x32 MFMA ----------------
template<int MODE>
__global__ __launch_bounds__(256) void gemm128(const unsigned short* __restrict__ A,
                                               const unsigned short* __restrict__ B,
                                               void* __restrict__ C,
                                               const float* __restrict__ eb2f, int K) {
  __shared__ __attribute__((aligned(16))) char As[2][16384];
  __shared__ __attribute__((aligned(16))) char Bs[2][16384];
  int tid = threadIdx.x, w = tid >> 6, lane = tid & 63;
  int l31 = lane & 31, hi = lane >> 5;
  int wr = w >> 1, wc = w & 1;
  int bm = blockIdx.x, bn = blockIdx.y;
  const char* Ab = (const char*)A + (size_t)bm * 128 * (K * 2);
  const char* Bb = (const char*)B + (size_t)bn * 128 * (K * 2);
  size_t ld = (size_t)K * 2;

  f32x16 acc00 = {}, acc01 = {}, acc10 = {}, acc11 = {};
  stage64(Ab, ld, As[0], w, lane);
  stage64(Ab + 64 * ld, ld, As[0] + 8192, w, lane);
  stage64(Bb, ld, Bs[0], w, lane);
  stage64(Bb + 64 * ld, ld, Bs[0] + 8192, w, lane);
  __syncthreads();

  int nst = K >> 6;
  for (int kk = 0; kk < nst; ++kk) {
    int cur = kk & 1;
    if (kk + 1 < nst) {
      const char* An = Ab + (size_t)(kk + 1) * 128;
      const char* Bn = Bb + (size_t)(kk + 1) * 128;
      stage64(An, ld, As[cur ^ 1], w, lane);
      stage64(An + 64 * ld, ld, As[cur ^ 1] + 8192, w, lane);
      stage64(Bn, ld, Bs[cur ^ 1], w, lane);
      stage64(Bn + 64 * ld, ld, Bs[cur ^ 1] + 8192, w, lane);
    }
    __builtin_amdgcn_s_setprio(1);
#pragma unroll
    for (int ks = 0; ks < 4; ++ks) {
      bf16x8 a0 = rdfrag32(As[cur], wr * 64 + l31, ks * 2 + hi);
      bf16x8 a1 = rdfrag32(As[cur], wr * 64 + 32 + l31, ks * 2 + hi);
      bf16x8 b0 = rdfrag32(Bs[cur], wc * 64 + l31, ks * 2 + hi);
      bf16x8 b1 = rdfrag32(Bs[cur], wc * 64 + 32 + l31, ks * 2 + hi);
      acc00 = __builtin_amdgcn_mfma_f32_32x32x16_bf16(a0, b0, acc00, 0, 0, 0);
      acc01 = __builtin_amdgcn_mfma_f32_32x32x16_bf16(a0, b1, acc01, 0, 0, 0);
      acc10 = __builtin_amdgcn_mfma_f32_32x32x16_bf16(a1, b0, acc10, 0, 0, 0);
      acc11 = __builtin_amdgcn_mfma_f32_32x32x16_bf16(a1, b1, acc11, 0, 0, 0);
    }
    __builtin_amdgcn_s_setprio(0);
    __syncthreads();
  }

  if (MODE == 0) {
    unsigned short* vt = (unsigned short*)C;
#pragma unroll
    for (int i = 0; i < 2; ++i) {
      int rowb = bm * 128 + wr * 64 + i * 32;
#pragma unroll
      for (int qd = 0; qd < 4; ++qd) {
        int m0 = rowb + qd * 8 + hi * 4;
        float4 e4 = *(const float4*)(eb2f + (m0 & 2047));   // seq pos = m0 mod 2048
        int bb = m0 >> 11, n = m0 & 2047;
#pragma unroll
        for (int j = 0; j < 2; ++j) {
          int h = bn * 2 + wc, d = j * 32 + l31;
          f32x16 a = (i == 0) ? (j == 0 ? acc00 : acc01) : (j == 0 ? acc10 : acc11);
          int r0 = qd * 4;
          uint2 u;
          u.x = (unsigned)f2bf(a[r0] * e4.x) | ((unsigned)f2bf(a[r0 + 1] * e4.y) << 16);
          u.y = (unsigned)f2bf(a[r0 + 2] * e4.z) | ((unsigned)f2bf(a[r0 + 3] * e4.w) << 16);
          *(uint2*)(vt + ((size_t)((bb * 16 + h) * 64 + d)) * 2048 + n) = u;
        }
      }
    }
  } else {
    float* Cf = (float*)C;
    int rb = bm * 128 + wr * 64, cb = bn * 128 + wc * 64;
#pragma unroll
    for (int r = 0; r < 16; ++r) {
      int row = (r & 3) + 8 * (r >> 2) + 4 * hi;
      Cf[(size_t)(rb + row) * 1024 + cb + l31]          = acc00[r];
      Cf[(size_t)(rb + row) * 1024 + cb + 32 + l31]     = acc01[r];
      Cf[(size_t)(rb + 32 + row) * 1024 + cb + l31]     = acc10[r];
      Cf[(size_t)(rb + 32 + row) * 1024 + cb + 32 + l31] = acc11[r];
    }
  }
}

// ---------------- fused dense attention (8-wave, m-parallel groups) ----------
// Block: 128 q rows, 8 waves. Group grp=w>>2: grp0 even m-tiles, grp1 odd.
// 4-slot LDS ring (K 4x8KB + V 4x8KB = 64KB); stage 2 tiles ahead; one barrier
// per superstep (2 tiles). End: O/L combined across groups via LDS (exact fp32).
__global__ __launch_bounds__(512, 4) void flash_kernel(const unsigned short* __restrict__ xb,
                                                       const unsigned short* __restrict__ w1b,
                                                       const float* __restrict__ b1,
                                                       const unsigned short* __restrict__ w2b,
                                                       const unsigned short* __restrict__ ebb,
                                                       const unsigned short* __restrict__ vt,
                                                       unsigned short* __restrict__ aout) {
  __shared__ __attribute__((aligned(16))) char lds[65536];
  int tid = threadIdx.x, w = tid >> 6, lane = tid & 63;
  int wq = w & 3, grp = w >> 2;
  int l31 = lane & 31, hi = lane >> 5;
  // XCD-chunked swizzle: 512 blocks, 8 XCDs
  int f = blockIdx.x;
  int swz = ((f & 7) << 6) | (f >> 3);
  int qt = swz & 15, bh = swz >> 4;
  int b = bh >> 4, h = bh & 15;

  // ---- prologue: Q = relu(xh @ W1^T + b1) * log2e, in-register ----
  const char* px = (const char*)(xb + ((size_t)(b * 2048 + qt * 128)) * 1024 + h * 64);
  stage8(px, 2048, lds, w, lane);                          // x rows 0..63
  stage8(px + (size_t)64 * 2048, 2048, lds + 8192, w, lane); // x rows 64..127
  stage8((const char*)w1b, 128, lds + 32768, w, lane);     // W1 rows e 0..63
  __syncthreads();

  f32x16 h0 = loadb16(b1 + hi * 4);
  f32x16 h1 = loadb16(b1 + 32 + hi * 4);
  {
    const char* xt = lds + (wq >> 1) * 8192;
    int xr = (wq & 1) * 32 + l31;
#pragma unroll
    for (int ks = 0; ks < 4; ++ks) {
      bf16x8 xf = rdfrag32(xt, xr, ks * 2 + hi);           // B: x^T (col=q)
      bf16x8 wf0 = rdfrag32(lds + 32768, l31, ks * 2 + hi);
      h0 = __builtin_amdgcn_mfma_f32_32x32x16_bf16(wf0, xf, h0, 0, 0, 0);
      bf16x8 wf1 = rdfrag32(lds + 32768, 32 + l31, ks * 2 + hi);
      h1 = __builtin_amdgcn_mfma_f32_32x32x16_bf16(wf1, xf, h1, 0, 0, 0);
    }
  }
#pragma unroll
  for (int i = 0; i < 16; ++i) {
    h0[i] = fmaxf(h0[i], 0.f) * LOG2E;
    h1[i] = fmaxf(h1[i], 0.f) * LOG2E;
  }
  bf16x8 qb[4];
  qb[0] = pk_swap(h0[0], h0[1], h0[2], h0[3], h0[4], h0[5], h0[6], h0[7]);
  qb[1] = pk_swap(h0[8], h0[9], h0[10], h0[11], h0[12], h0[13], h0[14], h0[15]);
  qb[2] = pk_swap(h1[0], h1[1], h1[2], h1[3], h1[4], h1[5], h1[6], h1[7]);
  qb[3] = pk_swap(h1[8], h1[9], h1[10], h1[11], h1[12], h1[13], h1[14], h1[15]);
  __syncthreads();                                  // all waves done with prologue LDS

  // ---- stage tiles 0..3 into the 4-slot ring ----
  const char* vtb = (const char*)vt + (size_t)bh * 64 * 4096;
#pragma unroll
  for (int t = 0; t < 4; ++t) {
    stage8((const char*)w2b + (size_t)t * 8192, 128, lds + t * 8192, w, lane);
    stage8(vtb + (size_t)t * 128, 4096, lds + 32768 + t * 8192, w, lane);
  }
  const f32x16 zro = {};
  f32x16 oA = {}, oB = {}, L = {};
  __syncthreads();                                  // tiles 0..3 landed

  for (int s = 0; s < 16; ++s) {
    int mt = 2 * s + grp;
    const char* Kc = lds + (mt & 3) * 8192;
    const char* Vc = lds + 32768 + (mt & 3) * 8192;

    bf16x8 ebf0 = *(const bf16x8*)(ebb + mt * 64 + hi * 8);
    bf16x8 ebf1 = *(const bf16x8*)(ebb + mt * 64 + 16 + hi * 8);
    bf16x8 ebf2 = *(const bf16x8*)(ebb + mt * 64 + 32 + hi * 8);
    bf16x8 ebf3 = *(const bf16x8*)(ebb + mt * 64 + 48 + hi * 8);

    // S^T = K @ Q (log2 domain)
    f32x16 s0 = zro, s1 = zro;
    __builtin_amdgcn_s_setprio(1);
#pragma unroll
    for (int kt = 0; kt < 4; ++kt) {
      bf16x8 kf0 = rdfrag32(Kc, l31, kt * 2 + hi);
      s0 = __builtin_amdgcn_mfma_f32_32x32x16_bf16(kf0, qb[kt], s0, 0, 0, 0);
      bf16x8 kf1 = rdfrag32(Kc, 32 + l31, kt * 2 + hi);
      s1 = __builtin_amdgcn_mfma_f32_32x32x16_bf16(kf1, qb[kt], s1, 0, 0, 0);
    }
    __builtin_amdgcn_s_setprio(0);
    // p = 2^s
#pragma unroll
    for (int i = 0; i < 16; ++i) {
      float t0, t1;
      asm("v_exp_f32 %0, %1" : "=v"(t0) : "v"(s0[i]));
      asm("v_exp_f32 %0, %1" : "=v"(t1) : "v"(s1[i]));
      s0[i] = t0; s1[i] = t1;
    }
    bf16x8 pa0 = pk_swap(s0[0], s0[1], s0[2], s0[3], s0[4], s0[5], s0[6], s0[7]);
    bf16x8 pa1 = pk_swap(s0[8], s0[9], s0[10], s0[11], s0[12], s0[13], s0[14], s0[15]);
    bf16x8 pa2 = pk_swap(s1[0], s1[1], s1[2], s1[3], s1[4], s1[5], s1[6], s1[7]);
    bf16x8 pa3 = pk_swap(s1[8], s1[9], s1[10], s1[11], s1[12], s1[13], s1[14], s1[15]);
    // O += P @ V ; L += P @ exp(b2)
    __builtin_amdgcn_s_setprio(1);
    L = __builtin_amdgcn_mfma_f32_32x32x16_bf16(pa0, ebf0, L, 0, 0, 0);
    L = __builtin_amdgcn_mfma_f32_32x32x16_bf16(pa1, ebf1, L, 0, 0, 0);
    L = __builtin_amdgcn_mfma_f32_32x32x16_bf16(pa2, ebf2, L, 0, 0, 0);
    L = __builtin_amdgcn_mfma_f32_32x32x16_bf16(pa3, ebf3, L, 0, 0, 0);
    {
      bf16x8 vf;
      vf = rdfrag32(Vc, l31, 0 + hi);
      oA = __builtin_amdgcn_mfma_f32_32x32x16_bf16(pa0, vf, oA, 0, 0, 0);
      vf = rdfrag32(Vc, 32 + l31, 0 + hi);
      oB = __builtin_amdgcn_mfma_f32_32x32x16_bf16(pa0, vf, oB, 0, 0, 0);
      vf = rdfrag32(Vc, l31, 2 + hi);
      oA = __builtin_amdgcn_mfma_f32_32x32x16_bf16(pa1, vf, oA, 0, 0, 0);
      vf = rdfrag32(Vc, 32 + l31, 2 + hi);
      oB = __builtin_amdgcn_mfma_f32_32x32x16_bf16(pa1, vf, oB, 0, 0, 0);
      vf = rdfrag32(Vc, l31, 4 + hi);
      oA = __builtin_amdgcn_mfma_f32_32x32x16_bf16(pa2, vf, oA, 0, 0, 0);
      vf = rdfrag32(Vc, 32 + l31, 4 + hi);
      oB = __builtin_amdgcn_mfma_f32_32x32x16_bf16(pa2, vf, oB, 0, 0, 0);
      vf = rdfrag32(Vc, l31, 6 + hi);
      oA = __builtin_amdgcn_mfma_f32_32x32x16_bf16(pa3, vf, oA, 0, 0, 0);
      vf = rdfrag32(Vc, 32 + l31, 6 + hi);
      oB = __builtin_amdgcn_mfma_f32_32x32x16_bf16(pa3, vf, oB, 0, 0, 0);
    }
    __builtin_amdgcn_s_setprio(0);
    __syncthreads();                       // both tiles of this superstep consumed
    if (s < 14) {                          // stage tiles 2s+4, 2s+5 (slots just freed)
      int t0 = 2 * s + 4, t1 = 2 * s + 5;
      stage8((const char*)w2b + (size_t)t0 * 8192, 128, lds + (t0 & 3) * 8192, w, lane);
      stage8(vtb + (size_t)t0 * 128, 4096, lds + 32768 + (t0 & 3) * 8192, w, lane);
      stage8((const char*)w2b + (size_t)t1 * 8192, 128, lds + (t1 & 3) * 8192, w, lane);
      stage8(vtb + (size_t)t1 * 128, 4096, lds + 32768 + (t1 & 3) * 8192, w, lane);
    }
  }

  // ---- combine groups (exact fp32 add), then finalize ----
  float* comb = (float*)lds;
  if (grp == 1) {
    float* cb = comb + (wq * 64 + lane) * 52;      // 52-float stride, 16B aligned
#pragma unroll
    for (int i = 0; i < 4; ++i) {
      *(float4*)(cb + i * 4)      = make_float4(oA[i*4], oA[i*4+1], oA[i*4+2], oA[i*4+3]);
      *(float4*)(cb + 16 + i * 4) = make_float4(oB[i*4], oB[i*4+1], oB[i*4+2], oB[i*4+3]);
      *(float4*)(cb + 32 + i * 4) = make_float4(L[i*4],  L[i*4+1],  L[i*4+2],  L[i*4+3]);
    }
  }
  __syncthreads();
  if (grp == 0) {
    float* cb = comb + (wq * 64 + lane) * 52;
#pragma unroll
    for (int i = 0; i < 4; ++i) {
      float4 a = *(const float4*)(cb + i * 4);
      float4 bq = *(const float4*)(cb + 16 + i * 4);
      float4 c = *(const float4*)(cb + 32 + i * 4);
      oA[i*4] += a.x; oA[i*4+1] += a.y; oA[i*4+2] += a.z; oA[i*4+3] += a.w;
      oB[i*4] += bq.x; oB[i*4+1] += bq.y; oB[i*4+2] += bq.z; oB[i*4+3] += bq.w;
      L[i*4] += c.x;  L[i*4+1] += c.y;  L[i*4+2] += c.z;  L[i*4+3] += c.w;
    }
    int nb = qt * 128 + wq * 32;
#pragma unroll
    for (int r = 0; r < 16; ++r) {
      float iv = 1.f / L[r];
      int ql = (r & 3) + 8 * (r >> 2) + 4 * hi;
      size_t off = ((size_t)(b * 2048 + nb + ql)) * 1024 + h * 64 + l31;
      aout[off]      = f2bf(oA[r] * iv);
      aout[off + 32] = f2bf(oB[r] * iv);
    }
  }
}

// ---------------- launch ----------------
extern "C" void kernel_launch(void* const* d_in, const int* in_sizes, int n_in,
                              void* d_out, int out_size, void* d_ws, size_t ws_size,
                              hipStream_t stream) {
  (void)in_sizes; (void)n_in; (void)out_size; (void)ws_size;
  const float* x  = (const float*)d_in[0];
  const float* W1 = (const float*)d_in[1];
  const float* b1 = (const float*)d_in[2];
  const float* W2 = (const float*)d_in[3];
  const float* b2 = (const float*)d_in[4];
  const float* Wv = (const float*)d_in[5];
  const float* Wo = (const float*)d_in[6];
  float* out = (float*)d_out;

  char* ws = (char*)d_ws;
  unsigned short* xb   = (unsigned short*)(ws);             // x bf16      8 MB
  unsigned short* wvb  = (unsigned short*)(ws +  8388608);  // Wv bf16     2 MB
  unsigned short* wob  = (unsigned short*)(ws + 10485760);  // Wo bf16     2 MB
  unsigned short* w2b  = (unsigned short*)(ws + 12582912);  // W2 bf16   256 KB
  unsigned short* w1b  = (unsigned short*)(ws + 12845056);  // W1 bf16     8 KB
  float*          eb2f = (float*)         (ws + 12853248);  // exp(b2)     8 KB
  unsigned short* ebb  = (unsigned short*)(ws + 12861440);  // exp(b2)bf16 4 KB
  unsigned short* vt   = (unsigned short*)(ws + 21233664);  // V^T bf16    8 MB
  unsigned short* aout = (unsigned short*)(ws + 29622272);  // out_h bf16  8 MB

  prep_all<<<2049, 256, 0, stream>>>(x, Wv, Wo, W2, W1, b2,
                                     xb, wvb, wob, w2b, w1b, eb2f, ebb);

  // value = x @ Wv^T (cols scaled by exp(b2)) -> vt[bh][d][m]
  gemm128<0><<<dim3(32, 8), 256, 0, stream>>>(xb, wvb, (void*)vt, eb2f, 1024);
  // fused: Q = relu(xh@W1^T+b1); softmax(Q@W2^T + b2) @ V -> aout (merged heads)
  flash_kernel<<<512, 512, 0, stream>>>(xb, w1b, b1, w2b, ebb, vt, aout);
  // out = aout @ Wo^T (fp32)
  gemm128<1><<<dim3(32, 8), 256, 0, stream>>>(aout, wob, (void*)out, eb2f, 1024);
}